// Round 8
// baseline (427.186 us; speedup 1.0000x reference)
//
#include <hip/hip_runtime.h>
#include <stdint.h>

#define SEQ   2048
#define DEMB  512
#define NH    8
#define DH    64
#define BATCH 8
#define M_ROWS (BATCH * SEQ)   // 16384
#define QKLD  1024             // qk buffer row stride (Q|K)
#define QSCALE 0.18033688011112042f   // 0.125 * log2(e)

typedef __attribute__((ext_vector_type(8))) __bf16 bf16x8;
typedef __attribute__((ext_vector_type(4))) __bf16 bf16x4;
typedef __attribute__((ext_vector_type(2))) __bf16 bf16x2;
typedef __attribute__((ext_vector_type(4))) float  f32x4;
typedef __attribute__((ext_vector_type(8))) uint16_t u16x8;
typedef __attribute__((ext_vector_type(4))) uint32_t u32x4;

__device__ __forceinline__ void gll16(const __bf16* g, __bf16* l) {
    __builtin_amdgcn_global_load_lds(
        (__attribute__((address_space(1))) void*)(__bf16*)g,
        (__attribute__((address_space(3))) void*)l, 16, 0, 0);
}

__device__ __forceinline__ bf16x8 ld8(const __bf16* p) {
    return *(const bf16x8*)p;
}

// pack two fp32 -> bf16 pair.  Vector-construction form (fptrunc +
// insertelement IR) so the backend can select v_cvt_pk_bf16_f32.
__device__ __forceinline__ uint32_t pkpair(float a, float b) {
    bf16x2 v;
    v[0] = (__bf16)a;
    v[1] = (__bf16)b;
    return __builtin_bit_cast(uint32_t, v);
}

// XOR-swizzled offset into a 64-wide bf16 LDS tile (8-elem chunks)
__device__ __forceinline__ int sw(int row, int chunk) {
    return row * 64 + ((chunk ^ (row & 7)) << 3);
}

// stage 64x64 bf16 tile into swizzled LDS via gll16 (swizzle on global col)
__device__ __forceinline__ void stage_gll_sw(const __bf16* g, int gld,
                                             __bf16* l, int wave, int lane) {
    const int lr = lane >> 3;
    const int scol = ((lane & 7) ^ lr) * 8;
    #pragma unroll
    for (int i = 0; i < 2; i++) {
        const int r0 = i * 32 + wave * 8;
        gll16(g + (size_t)(r0 + lr) * gld + scol, l + r0 * 64);
    }
}

// stage 128x64 bf16 tile via global_load_lds (16B/lane), unswizzled
__device__ __forceinline__ void stage_gll(const __bf16* src, __bf16* dst,
                                          int ld, int wave, int lane) {
    const int srow = lane >> 3, scol = (lane & 7) * 8;
    #pragma unroll
    for (int i = 0; i < 4; i++) {
        const int r0 = (i * 4 + wave) * 8;
        gll16(src + (size_t)(r0 + srow) * ld + scol, dst + r0 * 64);
    }
}

// ---------------------------------------------------------------------------
// fp32->bf16 converts
// ---------------------------------------------------------------------------
#define NXQ (M_ROWS * DEMB / 4)      // 2097152
#define NWQ (3 * DEMB * DEMB / 4)    // 196608
#define NOQ (DEMB * DEMB / 4)        // 65536

__global__ __launch_bounds__(256)
void cvt_all(const float* __restrict__ x, const float* __restrict__ w_in,
             __bf16* __restrict__ xb, __bf16* __restrict__ wb) {
    const int i = blockIdx.x * 256 + threadIdx.x;
    const float4* src;
    bf16x4* dst;
    if (i < NXQ) { src = (const float4*)x + i;         dst = (bf16x4*)xb + i; }
    else if (i < NXQ + NWQ) {
        const int j = i - NXQ;
        src = (const float4*)w_in + j;  dst = (bf16x4*)wb + j;
    } else return;
    const float4 v = *src;
    bf16x4 b;
    b[0] = (__bf16)v.x; b[1] = (__bf16)v.y;
    b[2] = (__bf16)v.z; b[3] = (__bf16)v.w;
    *dst = b;
}

__global__ __launch_bounds__(256)
void cvt_wout(const float* __restrict__ w, __bf16* __restrict__ wb) {
    const int i = blockIdx.x * 256 + threadIdx.x;
    if (i < NOQ) {
        const float4 v = ((const float4*)w)[i];
        bf16x4 b;
        b[0] = (__bf16)v.x; b[1] = (__bf16)v.y;
        b[2] = (__bf16)v.z; b[3] = (__bf16)v.w;
        ((bf16x4*)wb)[i] = b;
    }
}

// ---------------------------------------------------------------------------
// GEMM1: qkv = x_bf16 @ w_in_bf16^T + b_in.  Both operands via gll.
// Q cols pre-scaled by QSCALE.  Q,K -> qk[m][1024].
// Q/K blocks: MFMA operands SWAPPED (acc holds n on quad/reg axis) so the
//   epilogue writes bf16x4 (4 consecutive n) to swizzled LDS, then does
//   fully-coalesced bf16x8 row stores (replaces 64 scalar 2B global stores).
// V cols -> vt[(b*8+h)*64+d][s] via LDS transpose + coalesced 256B-row stores.
// ---------------------------------------------------------------------------
__global__ __launch_bounds__(256)
void gemm_qkv(const __bf16* __restrict__ A, const __bf16* __restrict__ W,
              const float* __restrict__ bias, __bf16* __restrict__ qk,
              __bf16* __restrict__ vt) {
    constexpr int K = DEMB;
    __shared__ __align__(16) __bf16 SM[128 * 128];   // As | Bs, reused for C
    __bf16* As = SM;
    __bf16* Bs = SM + 128 * 64;

    const int tid  = threadIdx.x;
    const int wave = tid >> 6, lane = tid & 63;
    const int quad = lane >> 4, l16 = lane & 15;
    const int m0 = blockIdx.x * 128, n0 = blockIdx.y * 128;
    const int wm = wave & 1, wn = wave >> 1;
    const bool qkblk = (n0 < QKLD);

    // qkblk: acc[j][i], output row-dim = n (quad*4+r), col-dim = m (l16)
    // else : acc[i][j], output row-dim = m (quad*4+r), col-dim = n (l16)
    f32x4 acc[4][4] = {};

    for (int k0 = 0; k0 < K; k0 += 64) {
        __syncthreads();
        stage_gll(A + (size_t)m0 * K + k0, As, K, wave, lane);
        stage_gll(W + (size_t)n0 * K + k0, Bs, K, wave, lane);
        __syncthreads();
        #pragma unroll
        for (int ks = 0; ks < 2; ks++) {
            bf16x8 af[4], bf[4];
            #pragma unroll
            for (int t = 0; t < 4; t++) {
                af[t] = ld8(&As[(wm * 64 + t * 16 + l16) * 64 + ks * 32 + quad * 8]);
                bf[t] = ld8(&Bs[(wn * 64 + t * 16 + l16) * 64 + ks * 32 + quad * 8]);
            }
            if (qkblk) {
                #pragma unroll
                for (int j = 0; j < 4; j++)
                    #pragma unroll
                    for (int i = 0; i < 4; i++)
                        acc[j][i] = __builtin_amdgcn_mfma_f32_16x16x32_bf16(
                            bf[j], af[i], acc[j][i], 0, 0, 0);
            } else {
                #pragma unroll
                for (int i = 0; i < 4; i++)
                    #pragma unroll
                    for (int j = 0; j < 4; j++)
                        acc[i][j] = __builtin_amdgcn_mfma_f32_16x16x32_bf16(
                            af[i], bf[j], acc[i][j], 0, 0, 0);
            }
        }
    }

    __syncthreads();   // all waves done reading As/Bs before SM reuse

    if (qkblk) {
        const float scl = (n0 < DEMB) ? QSCALE : 1.0f;   // pre-scale Q only
        // stage C[m][n] into swizzled SM: bf16x4 = 4 consecutive n per write
        #pragma unroll
        for (int j = 0; j < 4; j++) {
            const int nl = wn * 64 + j * 16 + quad * 4;
            const float4 bv4 = *(const float4*)&bias[n0 + nl];
            const int chunk = nl >> 3;                   // wn*8 + j*2 + (quad>>1)
            #pragma unroll
            for (int i = 0; i < 4; i++) {
                const int ml = wm * 64 + i * 16 + l16;
                bf16x4 pk;
                pk[0] = (__bf16)((acc[j][i][0] + bv4.x) * scl);
                pk[1] = (__bf16)((acc[j][i][1] + bv4.y) * scl);
                pk[2] = (__bf16)((acc[j][i][2] + bv4.z) * scl);
                pk[3] = (__bf16)((acc[j][i][3] + bv4.w) * scl);
                const int phys = ((chunk & 7) ^ (ml & 7)) | (chunk & 8);
                *(bf16x4*)(&SM[ml * 128 + phys * 8 + (nl & 7)]) = pk;
            }
        }
        __syncthreads();
        // coalesced stores: 16 lanes cover one 256B row of qk
        const int g = tid >> 4, li = tid & 15;
        #pragma unroll
        for (int it = 0; it < 8; it++) {
            const int row = it * 16 + g;
            const int phys = ((li & 7) ^ (row & 7)) | (li & 8);
            bf16x8 v = ld8(&SM[row * 128 + phys * 8]);
            *(bf16x8*)(qk + (size_t)(m0 + row) * QKLD + n0 + li * 8) = v;
        }
    } else {
        // V block: transpose 128(hd) x 128(s) through swizzled LDS
        const int hd0 = n0 - QKLD;             // 0,128,256,384
        const int bb = m0 >> 11, s0 = m0 & (SEQ - 1);
        #pragma unroll
        for (int j = 0; j < 4; j++) {
            const int n = n0 + wn * 64 + j * 16 + l16;
            const float bv = bias[n];
            const int hdl = wn * 64 + j * 16 + l16;      // local hd row
            #pragma unroll
            for (int i = 0; i < 4; i++) {
                const int sl = wm * 64 + i * 16 + quad * 4;  // local s (4-aligned)
                bf16x4 pk;
                #pragma unroll
                for (int r = 0; r < 4; r++)
                    pk[r] = (__bf16)(acc[i][j][r] + bv);
                const int chunk = sl >> 3;               // 0..15
                const int phys = (((chunk & 7) ^ (hdl & 7)) | (chunk & 8));
                *(bf16x4*)(&SM[hdl * 128 + phys * 8 + (sl & 7)]) = pk;
            }
        }
        __syncthreads();
        // coalesced stores: 16 lanes cover one 256B row
        const int g = tid >> 4, li = tid & 15;
        #pragma unroll
        for (int it = 0; it < 8; it++) {
            const int row = it * 16 + g;
            const int phys = (((li & 7) ^ (row & 7)) | (li & 8));
            bf16x8 v = ld8(&SM[row * 128 + phys * 8]);
            *(bf16x8*)(vt + ((size_t)(bb * DEMB + hd0 + row)) * SEQ + s0 + li * 8) = v;
        }
    }
}

// ---------------------------------------------------------------------------
// Flash attention, S^T formulation, software-pipelined across k-tiles
// (round-6 structure, REVERTED to direct blockIdx mapping: the XCD head-
// pinning remap concentrated each XCD's K/V footprint to exactly its 4MB L2
// -> pathological thrash, FETCH 139->517MB, attn 90->262us.  The natural
// dispatch's temporal clustering (16 consecutive blocks share one head,
// whole grid co-resident) already gives ~3.7x K/V L2 reuse.)
// pkpair via bf16x2 vector construction (v_cvt_pk_bf16_f32 selection).
// ---------------------------------------------------------------------------
__global__ __launch_bounds__(256, 4)
void attn_flash(const __bf16* __restrict__ qk, const __bf16* __restrict__ vt,
                __bf16* __restrict__ outp) {
    const int qt = blockIdx.x, h = blockIdx.y, b = blockIdx.z;
    const int tid  = threadIdx.x;
    const int wave = tid >> 6, lane = tid & 63;
    const int quad = lane >> 4, l16 = lane & 15;

    __shared__ __align__(16) __bf16 Ks[2][64 * 64];   // 16 KB
    __shared__ __align__(16) __bf16 Vt[2][64 * 64];   // 16 KB

    const size_t brow = (size_t)b * SEQ;
    const int q0 = qt * 128 + wave * 32;
    const __bf16* kbase = qk + brow * QKLD + DEMB + h * DH;
    const __bf16* vbase = vt + ((size_t)(b * DEMB + h * DH)) * SEQ;

    const u16x8 one16 = {0x3F80, 0x3F80, 0x3F80, 0x3F80,
                         0x3F80, 0x3F80, 0x3F80, 0x3F80};
    const bf16x8 ONES = __builtin_bit_cast(bf16x8, one16);

    // Q fragments (B-operand: B[k=quad*8+j][n=l16] = Q[q=l16][d])
    bf16x8 qf[2][2];
    #pragma unroll
    for (int qb = 0; qb < 2; qb++) {
        const __bf16* qp = qk + (brow + q0 + qb * 16 + l16) * QKLD + h * DH + quad * 8;
        qf[qb][0] = ld8(qp);
        qf[qb][1] = ld8(qp + 32);
    }

    f32x4 o[2][4] = {};
    f32x4 osum[2] = {};
    uint32_t pk[2][4][2];    // packed exp2'd scores, carried across iterations
    bf16x8 pf[2][2];         // P fragments of the tile being PV'd

    // QK^T + fused exp2 + pack for tile tt:
    // pk[qb][kt][rp] = bf16 pair of keys (16kt + 4*quad + 2rp, +1) at q=l16
    auto do_qkexp = [&](int tt) {
        const int bufq = tt & 1;
        #pragma unroll
        for (int kt = 0; kt < 4; kt++) {
            bf16x8 kf0 = ld8(&Ks[bufq][sw(kt * 16 + l16, quad)]);
            bf16x8 kf1 = ld8(&Ks[bufq][sw(kt * 16 + l16, 4 + quad)]);
            #pragma unroll
            for (int qb = 0; qb < 2; qb++) {
                f32x4 c = {};
                c = __builtin_amdgcn_mfma_f32_16x16x32_bf16(kf0, qf[qb][0], c, 0, 0, 0);
                c = __builtin_amdgcn_mfma_f32_16x16x32_bf16(kf1, qf[qb][1], c, 0, 0, 0);
                pk[qb][kt][0] = pkpair(__builtin_amdgcn_exp2f(c[0]),
                                       __builtin_amdgcn_exp2f(c[1]));
                pk[qb][kt][1] = pkpair(__builtin_amdgcn_exp2f(c[2]),
                                       __builtin_amdgcn_exp2f(c[3]));
            }
        }
    };

    // in-register quad transpose (permlane swaps) + rowsum
    // target: pf[qb][f] = A-frag, dword jp = keys (32f + 8*quad + 2jp, +1)
    auto do_permlane_osum = [&]() {
        #pragma unroll
        for (int qb = 0; qb < 2; qb++) {
            #pragma unroll
            for (int f = 0; f < 2; f++) {
                uint32_t a0 = pk[qb][2 * f][0], b0 = pk[qb][2 * f + 1][0];
                uint32_t a1 = pk[qb][2 * f][1], b1 = pk[qb][2 * f + 1][1];
                {
                    auto r = __builtin_amdgcn_permlane32_swap(a0, b0, false, false);
                    a0 = r[0]; b0 = r[1];
                }
                {
                    auto r = __builtin_amdgcn_permlane32_swap(a1, b1, false, false);
                    a1 = r[0]; b1 = r[1];
                }
                {
                    auto r = __builtin_amdgcn_permlane16_swap(a0, b0, false, false);
                    a0 = r[0]; b0 = r[1];
                }
                {
                    auto r = __builtin_amdgcn_permlane16_swap(a1, b1, false, false);
                    a1 = r[0]; b1 = r[1];
                }
                u32x4 d;
                d[0] = a0; d[1] = a1; d[2] = b0; d[3] = b1;
                pf[qb][f] = __builtin_bit_cast(bf16x8, d);
            }
            osum[qb] = __builtin_amdgcn_mfma_f32_16x16x32_bf16(pf[qb][0], ONES, osum[qb], 0, 0, 0);
            osum[qb] = __builtin_amdgcn_mfma_f32_16x16x32_bf16(pf[qb][1], ONES, osum[qb], 0, 0, 0);
        }
    };

    auto do_pv = [&](int tt) {
        const int bufv = tt & 1;
        #pragma unroll
        for (int db = 0; db < 4; db++) {
            bf16x8 vf0 = ld8(&Vt[bufv][sw(db * 16 + l16, quad)]);
            bf16x8 vf1 = ld8(&Vt[bufv][sw(db * 16 + l16, 4 + quad)]);
            #pragma unroll
            for (int qb = 0; qb < 2; qb++) {
                o[qb][db] = __builtin_amdgcn_mfma_f32_16x16x32_bf16(pf[qb][0], vf0, o[qb][db], 0, 0, 0);
                o[qb][db] = __builtin_amdgcn_mfma_f32_16x16x32_bf16(pf[qb][1], vf1, o[qb][db], 0, 0, 0);
            }
        }
    };

    constexpr int NT = SEQ / 64;

    // prologue: K0, V0, K1 staged; QKexp(0) computed
    stage_gll_sw(kbase,                      QKLD, Ks[0], wave, lane);
    stage_gll_sw(vbase,                      SEQ,  Vt[0], wave, lane);
    stage_gll_sw(kbase + (size_t)64 * QKLD,  QKLD, Ks[1], wave, lane);
    __syncthreads();
    do_qkexp(0);

    for (int t = 0; t < NT - 1; ++t) {
        __syncthreads();
        // stage K[t+2] into Ks[t&1] (QKexp(t) read of it finished pre-barrier);
        // stage V[t+1] into Vt[(t+1)&1] (PV(t-1) read finished pre-barrier)
        if (t + 2 < NT)
            stage_gll_sw(kbase + (size_t)(t + 2) * 64 * QKLD, QKLD, Ks[t & 1], wave, lane);
        stage_gll_sw(vbase + (t + 1) * 64, SEQ, Vt[(t + 1) & 1], wave, lane);

        do_permlane_osum();              // consumes pk(t) -> pf
        __builtin_amdgcn_s_setprio(1);
        do_pv(t);                        // MFMA: pf x Vt[t&1]
        do_qkexp(t + 1);                 // MFMA+exp2 -> pk(t+1), Ks[(t+1)&1]
        __builtin_amdgcn_s_setprio(0);
    }

    // tail: permlane + rowsum + PV of the last tile
    __syncthreads();
    do_permlane_osum();
    do_pv(NT - 1);

    // normalize + store (o, osum share C-layout: row=quad*4+r=q, col=l16=d)
    #pragma unroll
    for (int qb = 0; qb < 2; qb++)
        #pragma unroll
        for (int r = 0; r < 4; r++) {
            const float linv = __builtin_amdgcn_rcpf(osum[qb][r]);
            const int q = q0 + qb * 16 + quad * 4 + r;
            #pragma unroll
            for (int db = 0; db < 4; db++)
                outp[(brow + q) * DEMB + h * DH + db * 16 + l16] =
                    (__bf16)(o[qb][db][r] * linv);
        }
}

// ---------------------------------------------------------------------------
// GEMM2: out = attn @ w_out_bf16^T + b_out  (both via gll, fp32 out).
// MFMA operands SWAPPED so acc holds 4 consecutive n per fragment; epilogue
// stages fp32 through LDS (two 64-row passes over the 32KB As|Bs space) and
// does fully-coalesced float4 stores (replaces 64 scalar 4B global stores).
// ---------------------------------------------------------------------------
__global__ __launch_bounds__(256)
void gemm_out(const __bf16* __restrict__ A, const __bf16* __restrict__ W,
              const float* __restrict__ bias, float* __restrict__ C,
              int N, int K) {
    __shared__ __align__(16) __bf16 SMO[2 * 128 * 64];   // As|Bs, reused fp32
    __bf16* As = SMO;
    __bf16* Bs = SMO + 128 * 64;

    const int tid  = threadIdx.x;
    const int wave = tid >> 6, lane = tid & 63;
    const int quad = lane >> 4, l16 = lane & 15;
    const int m0 = blockIdx.x * 128, n0 = blockIdx.y * 128;
    const int wm = wave & 1, wn = wave >> 1;

    // acc[j][i]: output row-dim = n (quad*4+r), col-dim = m (l16)
    f32x4 acc[4][4] = {};

    for (int k0 = 0; k0 < K; k0 += 64) {
        __syncthreads();
        stage_gll(A + (size_t)m0 * K + k0, As, K, wave, lane);
        stage_gll(W + (size_t)n0 * K + k0, Bs, K, wave, lane);
        __syncthreads();
        #pragma unroll
        for (int ks = 0; ks < 2; ks++) {
            bf16x8 af[4], bf[4];
            #pragma unroll
            for (int t = 0; t < 4; t++) {
                af[t] = ld8(&As[(wm * 64 + t * 16 + l16) * 64 + ks * 32 + quad * 8]);
                bf[t] = ld8(&Bs[(wn * 64 + t * 16 + l16) * 64 + ks * 32 + quad * 8]);
            }
            #pragma unroll
            for (int j = 0; j < 4; j++)
                #pragma unroll
                for (int i = 0; i < 4; i++)
                    acc[j][i] = __builtin_amdgcn_mfma_f32_16x16x32_bf16(
                        bf[j], af[i], acc[j][i], 0, 0, 0);
        }
    }

    __syncthreads();   // all waves done reading As/Bs
    float* SMf = (float*)SMO;     // 64 rows x 128 cols fp32 per pass = 32KB

    #pragma unroll
    for (int p = 0; p < 2; p++) {
        if (p) __syncthreads();   // pass-0 reads done before pass-1 writes
        if (wm == p) {
            #pragma unroll
            for (int j = 0; j < 4; j++) {
                const int nl = wn * 64 + j * 16 + quad * 4;
                const float4 bv4 = *(const float4*)&bias[n0 + nl];
                const int chunkf = nl >> 2;              // 0..31 (16B chunks)
                #pragma unroll
                for (int i = 0; i < 4; i++) {
                    const int ml = i * 16 + l16;         // local row 0..63
                    const int physf = ((chunkf & 7) ^ (ml & 7)) | (chunkf & 24);
                    float4 v;
                    v.x = acc[j][i][0] + bv4.x;
                    v.y = acc[j][i][1] + bv4.y;
                    v.z = acc[j][i][2] + bv4.z;
                    v.w = acc[j][i][3] + bv4.w;
                    *(float4*)(&SMf[ml * 128 + physf * 4]) = v;
                }
            }
        }
        __syncthreads();
        // coalesced stores: 32 lanes cover one 512B row
        const int g2 = tid >> 5, li2 = tid & 31;
        #pragma unroll
        for (int it = 0; it < 8; it++) {
            const int row = it * 8 + g2;
            const int physf = ((li2 & 7) ^ (row & 7)) | (li2 & 24);
            float4 v = *(const float4*)&SMf[row * 128 + physf * 4];
            *(float4*)(&C[(size_t)(m0 + p * 64 + row) * N + n0 + li2 * 4]) = v;
        }
    }
}

// ---------------------------------------------------------------------------
extern "C" void kernel_launch(void* const* d_in, const int* in_sizes, int n_in,
                              void* d_out, int out_size, void* d_ws, size_t ws_size,
                              hipStream_t stream) {
    const float* x     = (const float*)d_in[0];
    const float* w_in  = (const float*)d_in[1];
    const float* b_in  = (const float*)d_in[2];
    const float* w_out = (const float*)d_in[3];
    const float* b_out = (const float*)d_in[4];

    __bf16* qk   = (__bf16*)d_ws;                    // 16384x1024 = 32 MB
    __bf16* vtb  = qk + (size_t)M_ROWS * QKLD;       // 4096x2048  = 16 MB
    __bf16* xbuf = vtb + (size_t)BATCH * DEMB * SEQ; // 16 MB, ALIASED with aout
    __bf16* aout = xbuf;                             // x_bf16 dead before attn writes
    __bf16* woutb = vtb;                             // vtb dead after attn
    __bf16* winb = (__bf16*)((char*)d_out + 24u * 1024 * 1024);  // 1.5 MB of d_out
    float*  outp = (float*)d_out;

    cvt_all<<<(NXQ + NWQ + 255) / 256, 256, 0, stream>>>(x, w_in, xbuf, winb);
    gemm_qkv<<<dim3(M_ROWS / 128, 12), 256, 0, stream>>>(xbuf, winb, b_in, qk, vtb);
    attn_flash<<<dim3(SEQ / 128, NH, BATCH), 256, 0, stream>>>(qk, vtb, aout);
    cvt_wout<<<NOQ / 256, 256, 0, stream>>>(w_out, woutb);
    gemm_out<<<dim3(M_ROWS / 128, DEMB / 128), 256, 0, stream>>>(
        aout, woutb, b_out, outp, DEMB, DEMB);
}

// Round 9
// 232.143 us; speedup vs baseline: 1.8402x; 1.8402x over previous
//
#include <hip/hip_runtime.h>
#include <stdint.h>

#define SEQ   2048
#define DEMB  512
#define NH    8
#define DH    64
#define BATCH 8
#define M_ROWS (BATCH * SEQ)   // 16384
#define QKLD  1024             // qk buffer row stride (Q|K)
#define QSCALE 0.18033688011112042f   // 0.125 * log2(e)

typedef __attribute__((ext_vector_type(8))) __bf16 bf16x8;
typedef __attribute__((ext_vector_type(4))) __bf16 bf16x4;
typedef __attribute__((ext_vector_type(4))) float  f32x4;
typedef __attribute__((ext_vector_type(8))) uint16_t u16x8;
typedef __attribute__((ext_vector_type(4))) uint32_t u32x4;

__device__ __forceinline__ void gll16(const __bf16* g, __bf16* l) {
    __builtin_amdgcn_global_load_lds(
        (__attribute__((address_space(1))) void*)(__bf16*)g,
        (__attribute__((address_space(3))) void*)l, 16, 0, 0);
}

__device__ __forceinline__ bf16x8 ld8(const __bf16* p) {
    return *(const bf16x8*)p;
}

// pack two fp32 -> bf16 pair via plain casts + integer merge.
// NOTE (round-8 lesson): do NOT use a bf16x2 vector-element-insert form here.
// That form fails SROA on this compiler, the loop-carried pk[][] aggregate
// becomes address-taken and spills to SCRATCH: WRITE_SIZE exploded 16->549MB
// and attn went 90->280us.  This scalar-cast + or form is hazard-visible and
// stays in registers (measured: round 6, 89.8us).
__device__ __forceinline__ uint32_t pkpair(float a, float b) {
    const uint16_t lo = __builtin_bit_cast(uint16_t, (__bf16)a);
    const uint16_t hi = __builtin_bit_cast(uint16_t, (__bf16)b);
    return (uint32_t)lo | ((uint32_t)hi << 16);
}

// XOR-swizzled offset into a 64-wide bf16 LDS tile (8-elem chunks)
__device__ __forceinline__ int sw(int row, int chunk) {
    return row * 64 + ((chunk ^ (row & 7)) << 3);
}

// stage 64x64 bf16 tile into swizzled LDS via gll16 (swizzle on global col)
__device__ __forceinline__ void stage_gll_sw(const __bf16* g, int gld,
                                             __bf16* l, int wave, int lane) {
    const int lr = lane >> 3;
    const int scol = ((lane & 7) ^ lr) * 8;
    #pragma unroll
    for (int i = 0; i < 2; i++) {
        const int r0 = i * 32 + wave * 8;
        gll16(g + (size_t)(r0 + lr) * gld + scol, l + r0 * 64);
    }
}

// stage 128x64 bf16 tile via global_load_lds (16B/lane), unswizzled
__device__ __forceinline__ void stage_gll(const __bf16* src, __bf16* dst,
                                          int ld, int wave, int lane) {
    const int srow = lane >> 3, scol = (lane & 7) * 8;
    #pragma unroll
    for (int i = 0; i < 4; i++) {
        const int r0 = (i * 4 + wave) * 8;
        gll16(src + (size_t)(r0 + srow) * ld + scol, dst + r0 * 64);
    }
}

// ---------------------------------------------------------------------------
// fp32->bf16 converts
// ---------------------------------------------------------------------------
#define NXQ (M_ROWS * DEMB / 4)      // 2097152
#define NWQ (3 * DEMB * DEMB / 4)    // 196608
#define NOQ (DEMB * DEMB / 4)        // 65536

__global__ __launch_bounds__(256)
void cvt_all(const float* __restrict__ x, const float* __restrict__ w_in,
             __bf16* __restrict__ xb, __bf16* __restrict__ wb) {
    const int i = blockIdx.x * 256 + threadIdx.x;
    const float4* src;
    bf16x4* dst;
    if (i < NXQ) { src = (const float4*)x + i;         dst = (bf16x4*)xb + i; }
    else if (i < NXQ + NWQ) {
        const int j = i - NXQ;
        src = (const float4*)w_in + j;  dst = (bf16x4*)wb + j;
    } else return;
    const float4 v = *src;
    bf16x4 b;
    b[0] = (__bf16)v.x; b[1] = (__bf16)v.y;
    b[2] = (__bf16)v.z; b[3] = (__bf16)v.w;
    *dst = b;
}

__global__ __launch_bounds__(256)
void cvt_wout(const float* __restrict__ w, __bf16* __restrict__ wb) {
    const int i = blockIdx.x * 256 + threadIdx.x;
    if (i < NOQ) {
        const float4 v = ((const float4*)w)[i];
        bf16x4 b;
        b[0] = (__bf16)v.x; b[1] = (__bf16)v.y;
        b[2] = (__bf16)v.z; b[3] = (__bf16)v.w;
        ((bf16x4*)wb)[i] = b;
    }
}

// ---------------------------------------------------------------------------
// GEMM1: qkv = x_bf16 @ w_in_bf16^T + b_in.  Both operands via gll.
// Q cols pre-scaled by QSCALE.  Q,K -> qk[m][1024].
// Q/K blocks: MFMA operands SWAPPED (acc holds n on quad/reg axis) so the
//   epilogue writes bf16x4 (4 consecutive n) to swizzled LDS, then does
//   fully-coalesced bf16x8 row stores (replaces 64 scalar 2B global stores).
// V cols -> vt[(b*8+h)*64+d][s] via LDS transpose + coalesced 256B-row stores.
// ---------------------------------------------------------------------------
__global__ __launch_bounds__(256)
void gemm_qkv(const __bf16* __restrict__ A, const __bf16* __restrict__ W,
              const float* __restrict__ bias, __bf16* __restrict__ qk,
              __bf16* __restrict__ vt) {
    constexpr int K = DEMB;
    __shared__ __align__(16) __bf16 SM[128 * 128];   // As | Bs, reused for C
    __bf16* As = SM;
    __bf16* Bs = SM + 128 * 64;

    const int tid  = threadIdx.x;
    const int wave = tid >> 6, lane = tid & 63;
    const int quad = lane >> 4, l16 = lane & 15;
    const int m0 = blockIdx.x * 128, n0 = blockIdx.y * 128;
    const int wm = wave & 1, wn = wave >> 1;
    const bool qkblk = (n0 < QKLD);

    // qkblk: acc[j][i], output row-dim = n (quad*4+r), col-dim = m (l16)
    // else : acc[i][j], output row-dim = m (quad*4+r), col-dim = n (l16)
    f32x4 acc[4][4] = {};

    for (int k0 = 0; k0 < K; k0 += 64) {
        __syncthreads();
        stage_gll(A + (size_t)m0 * K + k0, As, K, wave, lane);
        stage_gll(W + (size_t)n0 * K + k0, Bs, K, wave, lane);
        __syncthreads();
        #pragma unroll
        for (int ks = 0; ks < 2; ks++) {
            bf16x8 af[4], bf[4];
            #pragma unroll
            for (int t = 0; t < 4; t++) {
                af[t] = ld8(&As[(wm * 64 + t * 16 + l16) * 64 + ks * 32 + quad * 8]);
                bf[t] = ld8(&Bs[(wn * 64 + t * 16 + l16) * 64 + ks * 32 + quad * 8]);
            }
            if (qkblk) {
                #pragma unroll
                for (int j = 0; j < 4; j++)
                    #pragma unroll
                    for (int i = 0; i < 4; i++)
                        acc[j][i] = __builtin_amdgcn_mfma_f32_16x16x32_bf16(
                            bf[j], af[i], acc[j][i], 0, 0, 0);
            } else {
                #pragma unroll
                for (int i = 0; i < 4; i++)
                    #pragma unroll
                    for (int j = 0; j < 4; j++)
                        acc[i][j] = __builtin_amdgcn_mfma_f32_16x16x32_bf16(
                            af[i], bf[j], acc[i][j], 0, 0, 0);
            }
        }
    }

    __syncthreads();   // all waves done reading As/Bs before SM reuse

    if (qkblk) {
        const float scl = (n0 < DEMB) ? QSCALE : 1.0f;   // pre-scale Q only
        // stage C[m][n] into swizzled SM: bf16x4 = 4 consecutive n per write
        #pragma unroll
        for (int j = 0; j < 4; j++) {
            const int nl = wn * 64 + j * 16 + quad * 4;
            const float4 bv4 = *(const float4*)&bias[n0 + nl];
            const int chunk = nl >> 3;                   // wn*8 + j*2 + (quad>>1)
            #pragma unroll
            for (int i = 0; i < 4; i++) {
                const int ml = wm * 64 + i * 16 + l16;
                bf16x4 pk;
                pk[0] = (__bf16)((acc[j][i][0] + bv4.x) * scl);
                pk[1] = (__bf16)((acc[j][i][1] + bv4.y) * scl);
                pk[2] = (__bf16)((acc[j][i][2] + bv4.z) * scl);
                pk[3] = (__bf16)((acc[j][i][3] + bv4.w) * scl);
                const int phys = ((chunk & 7) ^ (ml & 7)) | (chunk & 8);
                *(bf16x4*)(&SM[ml * 128 + phys * 8 + (nl & 7)]) = pk;
            }
        }
        __syncthreads();
        // coalesced stores: 16 lanes cover one 256B row of qk
        const int g = tid >> 4, li = tid & 15;
        #pragma unroll
        for (int it = 0; it < 8; it++) {
            const int row = it * 16 + g;
            const int phys = ((li & 7) ^ (row & 7)) | (li & 8);
            bf16x8 v = ld8(&SM[row * 128 + phys * 8]);
            *(bf16x8*)(qk + (size_t)(m0 + row) * QKLD + n0 + li * 8) = v;
        }
    } else {
        // V block: transpose 128(hd) x 128(s) through swizzled LDS
        const int hd0 = n0 - QKLD;             // 0,128,256,384
        const int bb = m0 >> 11, s0 = m0 & (SEQ - 1);
        #pragma unroll
        for (int j = 0; j < 4; j++) {
            const int n = n0 + wn * 64 + j * 16 + l16;
            const float bv = bias[n];
            const int hdl = wn * 64 + j * 16 + l16;      // local hd row
            #pragma unroll
            for (int i = 0; i < 4; i++) {
                const int sl = wm * 64 + i * 16 + quad * 4;  // local s (4-aligned)
                bf16x4 pk;
                #pragma unroll
                for (int r = 0; r < 4; r++)
                    pk[r] = (__bf16)(acc[i][j][r] + bv);
                const int chunk = sl >> 3;               // 0..15
                const int phys = (((chunk & 7) ^ (hdl & 7)) | (chunk & 8));
                *(bf16x4*)(&SM[hdl * 128 + phys * 8 + (sl & 7)]) = pk;
            }
        }
        __syncthreads();
        // coalesced stores: 16 lanes cover one 256B row
        const int g = tid >> 4, li = tid & 15;
        #pragma unroll
        for (int it = 0; it < 8; it++) {
            const int row = it * 16 + g;
            const int phys = (((li & 7) ^ (row & 7)) | (li & 8));
            bf16x8 v = ld8(&SM[row * 128 + phys * 8]);
            *(bf16x8*)(vt + ((size_t)(bb * DEMB + hd0 + row)) * SEQ + s0 + li * 8) = v;
        }
    }
}

// ---------------------------------------------------------------------------
// Flash attention, S^T formulation, software-pipelined across k-tiles.
// Loop-carried state is the PACKED bf16 score tile pk[2][4][2] (16 regs):
// exp2+pack fused into the QK cluster.  Body overlaps {permlane+osum+PV}(t)
// with {QK+exp2+pack}(t+1) in the same wave.
// Direct blockIdx mapping (XCD head-pinning remap measured as L2 thrash).
// __launch_bounds__(256,4): 60 VGPR, 4 blocks/CU, occupancy ~36%.
// Buffering: K staged 2-ahead into Ks[t&1], V 1-ahead; one barrier per iter.
// LDS = 32KB.  (Round-6 proven configuration: attn 89.8us.)
// ---------------------------------------------------------------------------
__global__ __launch_bounds__(256, 4)
void attn_flash(const __bf16* __restrict__ qk, const __bf16* __restrict__ vt,
                __bf16* __restrict__ outp) {
    const int qt = blockIdx.x, h = blockIdx.y, b = blockIdx.z;
    const int tid  = threadIdx.x;
    const int wave = tid >> 6, lane = tid & 63;
    const int quad = lane >> 4, l16 = lane & 15;

    __shared__ __align__(16) __bf16 Ks[2][64 * 64];   // 16 KB
    __shared__ __align__(16) __bf16 Vt[2][64 * 64];   // 16 KB

    const size_t brow = (size_t)b * SEQ;
    const int q0 = qt * 128 + wave * 32;
    const __bf16* kbase = qk + brow * QKLD + DEMB + h * DH;
    const __bf16* vbase = vt + ((size_t)(b * DEMB + h * DH)) * SEQ;

    const u16x8 one16 = {0x3F80, 0x3F80, 0x3F80, 0x3F80,
                         0x3F80, 0x3F80, 0x3F80, 0x3F80};
    const bf16x8 ONES = __builtin_bit_cast(bf16x8, one16);

    // Q fragments (B-operand: B[k=quad*8+j][n=l16] = Q[q=l16][d])
    bf16x8 qf[2][2];
    #pragma unroll
    for (int qb = 0; qb < 2; qb++) {
        const __bf16* qp = qk + (brow + q0 + qb * 16 + l16) * QKLD + h * DH + quad * 8;
        qf[qb][0] = ld8(qp);
        qf[qb][1] = ld8(qp + 32);
    }

    f32x4 o[2][4] = {};
    f32x4 osum[2] = {};
    uint32_t pk[2][4][2];    // packed exp2'd scores, carried across iterations
    bf16x8 pf[2][2];         // P fragments of the tile being PV'd

    // QK^T + fused exp2 + pack for tile tt:
    // pk[qb][kt][rp] = bf16 pair of keys (16kt + 4*quad + 2rp, +1) at q=l16
    auto do_qkexp = [&](int tt) {
        const int bufq = tt & 1;
        #pragma unroll
        for (int kt = 0; kt < 4; kt++) {
            bf16x8 kf0 = ld8(&Ks[bufq][sw(kt * 16 + l16, quad)]);
            bf16x8 kf1 = ld8(&Ks[bufq][sw(kt * 16 + l16, 4 + quad)]);
            #pragma unroll
            for (int qb = 0; qb < 2; qb++) {
                f32x4 c = {};
                c = __builtin_amdgcn_mfma_f32_16x16x32_bf16(kf0, qf[qb][0], c, 0, 0, 0);
                c = __builtin_amdgcn_mfma_f32_16x16x32_bf16(kf1, qf[qb][1], c, 0, 0, 0);
                pk[qb][kt][0] = pkpair(__builtin_amdgcn_exp2f(c[0]),
                                       __builtin_amdgcn_exp2f(c[1]));
                pk[qb][kt][1] = pkpair(__builtin_amdgcn_exp2f(c[2]),
                                       __builtin_amdgcn_exp2f(c[3]));
            }
        }
    };

    // in-register quad transpose (permlane swaps) + rowsum
    // target: pf[qb][f] = A-frag, dword jp = keys (32f + 8*quad + 2jp, +1)
    auto do_permlane_osum = [&]() {
        #pragma unroll
        for (int qb = 0; qb < 2; qb++) {
            #pragma unroll
            for (int f = 0; f < 2; f++) {
                uint32_t a0 = pk[qb][2 * f][0], b0 = pk[qb][2 * f + 1][0];
                uint32_t a1 = pk[qb][2 * f][1], b1 = pk[qb][2 * f + 1][1];
                {
                    auto r = __builtin_amdgcn_permlane32_swap(a0, b0, false, false);
                    a0 = r[0]; b0 = r[1];
                }
                {
                    auto r = __builtin_amdgcn_permlane32_swap(a1, b1, false, false);
                    a1 = r[0]; b1 = r[1];
                }
                {
                    auto r = __builtin_amdgcn_permlane16_swap(a0, b0, false, false);
                    a0 = r[0]; b0 = r[1];
                }
                {
                    auto r = __builtin_amdgcn_permlane16_swap(a1, b1, false, false);
                    a1 = r[0]; b1 = r[1];
                }
                u32x4 d;
                d[0] = a0; d[1] = a1; d[2] = b0; d[3] = b1;
                pf[qb][f] = __builtin_bit_cast(bf16x8, d);
            }
            osum[qb] = __builtin_amdgcn_mfma_f32_16x16x32_bf16(pf[qb][0], ONES, osum[qb], 0, 0, 0);
            osum[qb] = __builtin_amdgcn_mfma_f32_16x16x32_bf16(pf[qb][1], ONES, osum[qb], 0, 0, 0);
        }
    };

    auto do_pv = [&](int tt) {
        const int bufv = tt & 1;
        #pragma unroll
        for (int db = 0; db < 4; db++) {
            bf16x8 vf0 = ld8(&Vt[bufv][sw(db * 16 + l16, quad)]);
            bf16x8 vf1 = ld8(&Vt[bufv][sw(db * 16 + l16, 4 + quad)]);
            #pragma unroll
            for (int qb = 0; qb < 2; qb++) {
                o[qb][db] = __builtin_amdgcn_mfma_f32_16x16x32_bf16(pf[qb][0], vf0, o[qb][db], 0, 0, 0);
                o[qb][db] = __builtin_amdgcn_mfma_f32_16x16x32_bf16(pf[qb][1], vf1, o[qb][db], 0, 0, 0);
            }
        }
    };

    constexpr int NT = SEQ / 64;

    // prologue: K0, V0, K1 staged; QKexp(0) computed
    stage_gll_sw(kbase,                      QKLD, Ks[0], wave, lane);
    stage_gll_sw(vbase,                      SEQ,  Vt[0], wave, lane);
    stage_gll_sw(kbase + (size_t)64 * QKLD,  QKLD, Ks[1], wave, lane);
    __syncthreads();
    do_qkexp(0);

    for (int t = 0; t < NT - 1; ++t) {
        __syncthreads();
        // stage K[t+2] into Ks[t&1] (QKexp(t) read of it finished pre-barrier);
        // stage V[t+1] into Vt[(t+1)&1] (PV(t-1) read finished pre-barrier)
        if (t + 2 < NT)
            stage_gll_sw(kbase + (size_t)(t + 2) * 64 * QKLD, QKLD, Ks[t & 1], wave, lane);
        stage_gll_sw(vbase + (t + 1) * 64, SEQ, Vt[(t + 1) & 1], wave, lane);

        do_permlane_osum();              // consumes pk(t) -> pf
        __builtin_amdgcn_s_setprio(1);
        do_pv(t);                        // MFMA: pf x Vt[t&1]
        do_qkexp(t + 1);                 // MFMA+exp2 -> pk(t+1), Ks[(t+1)&1]
        __builtin_amdgcn_s_setprio(0);
    }

    // tail: permlane + rowsum + PV of the last tile
    __syncthreads();
    do_permlane_osum();
    do_pv(NT - 1);

    // normalize + store (o, osum share C-layout: row=quad*4+r=q, col=l16=d)
    #pragma unroll
    for (int qb = 0; qb < 2; qb++)
        #pragma unroll
        for (int r = 0; r < 4; r++) {
            const float linv = __builtin_amdgcn_rcpf(osum[qb][r]);
            const int q = q0 + qb * 16 + quad * 4 + r;
            #pragma unroll
            for (int db = 0; db < 4; db++)
                outp[(brow + q) * DEMB + h * DH + db * 16 + l16] =
                    (__bf16)(o[qb][db][r] * linv);
        }
}

// ---------------------------------------------------------------------------
// GEMM2: out = attn @ w_out_bf16^T + b_out  (both via gll, fp32 out).
// MFMA operands SWAPPED so acc holds 4 consecutive n per fragment; epilogue
// stages fp32 through LDS (two 64-row passes over the 32KB As|Bs space) and
// does fully-coalesced float4 stores (replaces 64 scalar 4B global stores).
// ---------------------------------------------------------------------------
__global__ __launch_bounds__(256)
void gemm_out(const __bf16* __restrict__ A, const __bf16* __restrict__ W,
              const float* __restrict__ bias, float* __restrict__ C,
              int N, int K) {
    __shared__ __align__(16) __bf16 SMO[2 * 128 * 64];   // As|Bs, reused fp32
    __bf16* As = SMO;
    __bf16* Bs = SMO + 128 * 64;

    const int tid  = threadIdx.x;
    const int wave = tid >> 6, lane = tid & 63;
    const int quad = lane >> 4, l16 = lane & 15;
    const int m0 = blockIdx.x * 128, n0 = blockIdx.y * 128;
    const int wm = wave & 1, wn = wave >> 1;

    // acc[j][i]: output row-dim = n (quad*4+r), col-dim = m (l16)
    f32x4 acc[4][4] = {};

    for (int k0 = 0; k0 < K; k0 += 64) {
        __syncthreads();
        stage_gll(A + (size_t)m0 * K + k0, As, K, wave, lane);
        stage_gll(W + (size_t)n0 * K + k0, Bs, K, wave, lane);
        __syncthreads();
        #pragma unroll
        for (int ks = 0; ks < 2; ks++) {
            bf16x8 af[4], bf[4];
            #pragma unroll
            for (int t = 0; t < 4; t++) {
                af[t] = ld8(&As[(wm * 64 + t * 16 + l16) * 64 + ks * 32 + quad * 8]);
                bf[t] = ld8(&Bs[(wn * 64 + t * 16 + l16) * 64 + ks * 32 + quad * 8]);
            }
            #pragma unroll
            for (int j = 0; j < 4; j++)
                #pragma unroll
                for (int i = 0; i < 4; i++)
                    acc[j][i] = __builtin_amdgcn_mfma_f32_16x16x32_bf16(
                        bf[j], af[i], acc[j][i], 0, 0, 0);
        }
    }

    __syncthreads();   // all waves done reading As/Bs
    float* SMf = (float*)SMO;     // 64 rows x 128 cols fp32 per pass = 32KB

    #pragma unroll
    for (int p = 0; p < 2; p++) {
        if (p) __syncthreads();   // pass-0 reads done before pass-1 writes
        if (wm == p) {
            #pragma unroll
            for (int j = 0; j < 4; j++) {
                const int nl = wn * 64 + j * 16 + quad * 4;
                const float4 bv4 = *(const float4*)&bias[n0 + nl];
                const int chunkf = nl >> 2;              // 0..31 (16B chunks)
                #pragma unroll
                for (int i = 0; i < 4; i++) {
                    const int ml = i * 16 + l16;         // local row 0..63
                    const int physf = ((chunkf & 7) ^ (ml & 7)) | (chunkf & 24);
                    float4 v;
                    v.x = acc[j][i][0] + bv4.x;
                    v.y = acc[j][i][1] + bv4.y;
                    v.z = acc[j][i][2] + bv4.z;
                    v.w = acc[j][i][3] + bv4.w;
                    *(float4*)(&SMf[ml * 128 + physf * 4]) = v;
                }
            }
        }
        __syncthreads();
        // coalesced stores: 32 lanes cover one 512B row
        const int g2 = tid >> 5, li2 = tid & 31;
        #pragma unroll
        for (int it = 0; it < 8; it++) {
            const int row = it * 8 + g2;
            const int physf = ((li2 & 7) ^ (row & 7)) | (li2 & 24);
            float4 v = *(const float4*)&SMf[row * 128 + physf * 4];
            *(float4*)(&C[(size_t)(m0 + p * 64 + row) * N + n0 + li2 * 4]) = v;
        }
    }
}

// ---------------------------------------------------------------------------
extern "C" void kernel_launch(void* const* d_in, const int* in_sizes, int n_in,
                              void* d_out, int out_size, void* d_ws, size_t ws_size,
                              hipStream_t stream) {
    const float* x     = (const float*)d_in[0];
    const float* w_in  = (const float*)d_in[1];
    const float* b_in  = (const float*)d_in[2];
    const float* w_out = (const float*)d_in[3];
    const float* b_out = (const float*)d_in[4];

    __bf16* qk   = (__bf16*)d_ws;                    // 16384x1024 = 32 MB
    __bf16* vtb  = qk + (size_t)M_ROWS * QKLD;       // 4096x2048  = 16 MB
    __bf16* xbuf = vtb + (size_t)BATCH * DEMB * SEQ; // 16 MB, ALIASED with aout
    __bf16* aout = xbuf;                             // x_bf16 dead before attn writes
    __bf16* woutb = vtb;                             // vtb dead after attn
    __bf16* winb = (__bf16*)((char*)d_out + 24u * 1024 * 1024);  // 1.5 MB of d_out
    float*  outp = (float*)d_out;

    cvt_all<<<(NXQ + NWQ + 255) / 256, 256, 0, stream>>>(x, w_in, xbuf, winb);
    gemm_qkv<<<dim3(M_ROWS / 128, 12), 256, 0, stream>>>(xbuf, winb, b_in, qk, vtb);
    attn_flash<<<dim3(SEQ / 128, NH, BATCH), 256, 0, stream>>>(qk, vtb, aout);
    cvt_wout<<<NOQ / 256, 256, 0, stream>>>(w_out, woutb);
    gemm_out<<<dim3(M_ROWS / 128, DEMB / 128), 256, 0, stream>>>(
        aout, woutb, b_out, outp, DEMB, DEMB);
}

// Round 10
// 227.446 us; speedup vs baseline: 1.8782x; 1.0207x over previous
//
#include <hip/hip_runtime.h>
#include <stdint.h>

#define SEQ   2048
#define DEMB  512
#define NH    8
#define DH    64
#define BATCH 8
#define M_ROWS (BATCH * SEQ)   // 16384
#define QKLD  1024             // qk buffer row stride (Q|K)
#define QSCALE 0.18033688011112042f   // 0.125 * log2(e)

typedef __attribute__((ext_vector_type(8))) __bf16 bf16x8;
typedef __attribute__((ext_vector_type(4))) __bf16 bf16x4;
typedef __attribute__((ext_vector_type(4))) float  f32x4;
typedef __attribute__((ext_vector_type(8))) uint16_t u16x8;
typedef __attribute__((ext_vector_type(4))) uint32_t u32x4;

__device__ __forceinline__ void gll16(const __bf16* g, __bf16* l) {
    __builtin_amdgcn_global_load_lds(
        (__attribute__((address_space(1))) void*)(__bf16*)g,
        (__attribute__((address_space(3))) void*)l, 16, 0, 0);
}

__device__ __forceinline__ bf16x8 ld8(const __bf16* p) {
    return *(const bf16x8*)p;
}

// pack two fp32 -> bf16 pair via plain casts + integer merge.
// NOTE (round-8 lesson): do NOT use a bf16x2 vector-element-insert form here.
// That form fails SROA on this compiler, the loop-carried pk[][] aggregate
// becomes address-taken and spills to SCRATCH: WRITE_SIZE exploded 16->549MB
// and attn went 90->280us.  This scalar-cast + or form is hazard-visible and
// stays in registers (measured: round 6, 89.8us).
__device__ __forceinline__ uint32_t pkpair(float a, float b) {
    const uint16_t lo = __builtin_bit_cast(uint16_t, (__bf16)a);
    const uint16_t hi = __builtin_bit_cast(uint16_t, (__bf16)b);
    return (uint32_t)lo | ((uint32_t)hi << 16);
}

// XOR-swizzled offset into a 64-wide bf16 LDS tile (8-elem chunks).
// Logical element [row][chunk*8+e] lives at phys chunk' = chunk ^ (row&7).
// Bank math: unswizzled, a 64-wide row is 128B = exactly 32 banks, so a
// column-slice read (16 lanes, different rows, same chunk) hits the SAME 4
// banks 16-way (m136: ~5.7x).  The XOR spreads the 16 lanes across all 8
// chunk slots -> 2 lanes/bank-set = free.
__device__ __forceinline__ int sw(int row, int chunk) {
    return row * 64 + ((chunk ^ (row & 7)) << 3);
}

// stage 64x64 bf16 tile into swizzled LDS via gll16 (swizzle on global col)
__device__ __forceinline__ void stage_gll_sw(const __bf16* g, int gld,
                                             __bf16* l, int wave, int lane) {
    const int lr = lane >> 3;
    const int scol = ((lane & 7) ^ lr) * 8;
    #pragma unroll
    for (int i = 0; i < 2; i++) {
        const int r0 = i * 32 + wave * 8;
        gll16(g + (size_t)(r0 + lr) * gld + scol, l + r0 * 64);
    }
}

// stage 128x64 bf16 tile via global_load_lds (16B/lane), XOR-SWIZZLED via
// pre-swizzled global source column (gll16 LDS dest must stay wave-linear).
// Wave writes 8 rows/call (r0 multiple of 8), so row&7 == lane>>3: lane l
// fetches global chunk ((l&7) ^ (l>>3)) -> LDS phys chunk (l&7) holds
// logical chunk (l&7)^(row&7), matching sw() on the read side.
// (Round-10: this de-conflicts the GEMM ds_read_b128 fragment reads, which
// were 16-way bank-conflicted -- the GEMMs' hidden cost, est. ~90us.)
__device__ __forceinline__ void stage_gll(const __bf16* src, __bf16* dst,
                                          int ld, int wave, int lane) {
    const int srow = lane >> 3, scol = ((lane & 7) ^ srow) * 8;
    #pragma unroll
    for (int i = 0; i < 4; i++) {
        const int r0 = (i * 4 + wave) * 8;
        gll16(src + (size_t)(r0 + srow) * ld + scol, dst + r0 * 64);
    }
}

// ---------------------------------------------------------------------------
// fp32->bf16 converts
// ---------------------------------------------------------------------------
#define NXQ (M_ROWS * DEMB / 4)      // 2097152
#define NWQ (3 * DEMB * DEMB / 4)    // 196608
#define NOQ (DEMB * DEMB / 4)        // 65536

__global__ __launch_bounds__(256)
void cvt_all(const float* __restrict__ x, const float* __restrict__ w_in,
             __bf16* __restrict__ xb, __bf16* __restrict__ wb) {
    const int i = blockIdx.x * 256 + threadIdx.x;
    const float4* src;
    bf16x4* dst;
    if (i < NXQ) { src = (const float4*)x + i;         dst = (bf16x4*)xb + i; }
    else if (i < NXQ + NWQ) {
        const int j = i - NXQ;
        src = (const float4*)w_in + j;  dst = (bf16x4*)wb + j;
    } else return;
    const float4 v = *src;
    bf16x4 b;
    b[0] = (__bf16)v.x; b[1] = (__bf16)v.y;
    b[2] = (__bf16)v.z; b[3] = (__bf16)v.w;
    *dst = b;
}

__global__ __launch_bounds__(256)
void cvt_wout(const float* __restrict__ w, __bf16* __restrict__ wb) {
    const int i = blockIdx.x * 256 + threadIdx.x;
    if (i < NOQ) {
        const float4 v = ((const float4*)w)[i];
        bf16x4 b;
        b[0] = (__bf16)v.x; b[1] = (__bf16)v.y;
        b[2] = (__bf16)v.z; b[3] = (__bf16)v.w;
        ((bf16x4*)wb)[i] = b;
    }
}

// ---------------------------------------------------------------------------
// GEMM1: qkv = x_bf16 @ w_in_bf16^T + b_in.  Both operands via swizzled gll.
// Q cols pre-scaled by QSCALE.  Q,K -> qk[m][1024].
// Q/K blocks: MFMA operands SWAPPED (acc holds n on quad/reg axis) so the
//   epilogue writes bf16x4 (4 consecutive n) to swizzled LDS, then does
//   fully-coalesced bf16x8 row stores.
// V cols -> vt[(b*8+h)*64+d][s] via LDS transpose + coalesced 256B-row stores.
// ---------------------------------------------------------------------------
__global__ __launch_bounds__(256)
void gemm_qkv(const __bf16* __restrict__ A, const __bf16* __restrict__ W,
              const float* __restrict__ bias, __bf16* __restrict__ qk,
              __bf16* __restrict__ vt) {
    constexpr int K = DEMB;
    __shared__ __align__(16) __bf16 SM[128 * 128];   // As | Bs, reused for C
    __bf16* As = SM;
    __bf16* Bs = SM + 128 * 64;

    const int tid  = threadIdx.x;
    const int wave = tid >> 6, lane = tid & 63;
    const int quad = lane >> 4, l16 = lane & 15;
    const int m0 = blockIdx.x * 128, n0 = blockIdx.y * 128;
    const int wm = wave & 1, wn = wave >> 1;
    const bool qkblk = (n0 < QKLD);

    // qkblk: acc[j][i], output row-dim = n (quad*4+r), col-dim = m (l16)
    // else : acc[i][j], output row-dim = m (quad*4+r), col-dim = n (l16)
    f32x4 acc[4][4] = {};

    for (int k0 = 0; k0 < K; k0 += 64) {
        __syncthreads();
        stage_gll(A + (size_t)m0 * K + k0, As, K, wave, lane);
        stage_gll(W + (size_t)n0 * K + k0, Bs, K, wave, lane);
        __syncthreads();
        #pragma unroll
        for (int ks = 0; ks < 2; ks++) {
            bf16x8 af[4], bf[4];
            #pragma unroll
            for (int t = 0; t < 4; t++) {
                af[t] = ld8(&As[sw(wm * 64 + t * 16 + l16, ks * 4 + quad)]);
                bf[t] = ld8(&Bs[sw(wn * 64 + t * 16 + l16, ks * 4 + quad)]);
            }
            if (qkblk) {
                #pragma unroll
                for (int j = 0; j < 4; j++)
                    #pragma unroll
                    for (int i = 0; i < 4; i++)
                        acc[j][i] = __builtin_amdgcn_mfma_f32_16x16x32_bf16(
                            bf[j], af[i], acc[j][i], 0, 0, 0);
            } else {
                #pragma unroll
                for (int i = 0; i < 4; i++)
                    #pragma unroll
                    for (int j = 0; j < 4; j++)
                        acc[i][j] = __builtin_amdgcn_mfma_f32_16x16x32_bf16(
                            af[i], bf[j], acc[i][j], 0, 0, 0);
            }
        }
    }

    __syncthreads();   // all waves done reading As/Bs before SM reuse

    if (qkblk) {
        const float scl = (n0 < DEMB) ? QSCALE : 1.0f;   // pre-scale Q only
        // stage C[m][n] into swizzled SM: bf16x4 = 4 consecutive n per write
        #pragma unroll
        for (int j = 0; j < 4; j++) {
            const int nl = wn * 64 + j * 16 + quad * 4;
            const float4 bv4 = *(const float4*)&bias[n0 + nl];
            const int chunk = nl >> 3;                   // wn*8 + j*2 + (quad>>1)
            #pragma unroll
            for (int i = 0; i < 4; i++) {
                const int ml = wm * 64 + i * 16 + l16;
                bf16x4 pk;
                pk[0] = (__bf16)((acc[j][i][0] + bv4.x) * scl);
                pk[1] = (__bf16)((acc[j][i][1] + bv4.y) * scl);
                pk[2] = (__bf16)((acc[j][i][2] + bv4.z) * scl);
                pk[3] = (__bf16)((acc[j][i][3] + bv4.w) * scl);
                const int phys = ((chunk & 7) ^ (ml & 7)) | (chunk & 8);
                *(bf16x4*)(&SM[ml * 128 + phys * 8 + (nl & 7)]) = pk;
            }
        }
        __syncthreads();
        // coalesced stores: 16 lanes cover one 256B row of qk
        const int g = tid >> 4, li = tid & 15;
        #pragma unroll
        for (int it = 0; it < 8; it++) {
            const int row = it * 16 + g;
            const int phys = ((li & 7) ^ (row & 7)) | (li & 8);
            bf16x8 v = ld8(&SM[row * 128 + phys * 8]);
            *(bf16x8*)(qk + (size_t)(m0 + row) * QKLD + n0 + li * 8) = v;
        }
    } else {
        // V block: transpose 128(hd) x 128(s) through swizzled LDS
        const int hd0 = n0 - QKLD;             // 0,128,256,384
        const int bb = m0 >> 11, s0 = m0 & (SEQ - 1);
        #pragma unroll
        for (int j = 0; j < 4; j++) {
            const int n = n0 + wn * 64 + j * 16 + l16;
            const float bv = bias[n];
            const int hdl = wn * 64 + j * 16 + l16;      // local hd row
            #pragma unroll
            for (int i = 0; i < 4; i++) {
                const int sl = wm * 64 + i * 16 + quad * 4;  // local s (4-aligned)
                bf16x4 pk;
                #pragma unroll
                for (int r = 0; r < 4; r++)
                    pk[r] = (__bf16)(acc[i][j][r] + bv);
                const int chunk = sl >> 3;               // 0..15
                const int phys = (((chunk & 7) ^ (hdl & 7)) | (chunk & 8));
                *(bf16x4*)(&SM[hdl * 128 + phys * 8 + (sl & 7)]) = pk;
            }
        }
        __syncthreads();
        // coalesced stores: 16 lanes cover one 256B row
        const int g = tid >> 4, li = tid & 15;
        #pragma unroll
        for (int it = 0; it < 8; it++) {
            const int row = it * 16 + g;
            const int phys = (((li & 7) ^ (row & 7)) | (li & 8));
            bf16x8 v = ld8(&SM[row * 128 + phys * 8]);
            *(bf16x8*)(vt + ((size_t)(bb * DEMB + hd0 + row)) * SEQ + s0 + li * 8) = v;
        }
    }
}

// ---------------------------------------------------------------------------
// Flash attention, S^T formulation, software-pipelined across k-tiles.
// Loop-carried state is the PACKED bf16 score tile pk[2][4][2] (16 regs):
// exp2+pack fused into the QK cluster.  Body overlaps {permlane+osum+PV}(t)
// with {QK+exp2+pack}(t+1) in the same wave.
// Direct blockIdx mapping (XCD head-pinning remap measured as L2 thrash).
// __launch_bounds__(256,4): 60 VGPR, 4 blocks/CU, occupancy ~36%.
// Buffering: K staged 2-ahead into Ks[t&1], V 1-ahead; one barrier per iter.
// LDS = 32KB.  (Round-9 proven configuration: attn 88.7us.)  UNCHANGED.
// ---------------------------------------------------------------------------
__global__ __launch_bounds__(256, 4)
void attn_flash(const __bf16* __restrict__ qk, const __bf16* __restrict__ vt,
                __bf16* __restrict__ outp) {
    const int qt = blockIdx.x, h = blockIdx.y, b = blockIdx.z;
    const int tid  = threadIdx.x;
    const int wave = tid >> 6, lane = tid & 63;
    const int quad = lane >> 4, l16 = lane & 15;

    __shared__ __align__(16) __bf16 Ks[2][64 * 64];   // 16 KB
    __shared__ __align__(16) __bf16 Vt[2][64 * 64];   // 16 KB

    const size_t brow = (size_t)b * SEQ;
    const int q0 = qt * 128 + wave * 32;
    const __bf16* kbase = qk + brow * QKLD + DEMB + h * DH;
    const __bf16* vbase = vt + ((size_t)(b * DEMB + h * DH)) * SEQ;

    const u16x8 one16 = {0x3F80, 0x3F80, 0x3F80, 0x3F80,
                         0x3F80, 0x3F80, 0x3F80, 0x3F80};
    const bf16x8 ONES = __builtin_bit_cast(bf16x8, one16);

    // Q fragments (B-operand: B[k=quad*8+j][n=l16] = Q[q=l16][d])
    bf16x8 qf[2][2];
    #pragma unroll
    for (int qb = 0; qb < 2; qb++) {
        const __bf16* qp = qk + (brow + q0 + qb * 16 + l16) * QKLD + h * DH + quad * 8;
        qf[qb][0] = ld8(qp);
        qf[qb][1] = ld8(qp + 32);
    }

    f32x4 o[2][4] = {};
    f32x4 osum[2] = {};
    uint32_t pk[2][4][2];    // packed exp2'd scores, carried across iterations
    bf16x8 pf[2][2];         // P fragments of the tile being PV'd

    // QK^T + fused exp2 + pack for tile tt:
    // pk[qb][kt][rp] = bf16 pair of keys (16kt + 4*quad + 2rp, +1) at q=l16
    auto do_qkexp = [&](int tt) {
        const int bufq = tt & 1;
        #pragma unroll
        for (int kt = 0; kt < 4; kt++) {
            bf16x8 kf0 = ld8(&Ks[bufq][sw(kt * 16 + l16, quad)]);
            bf16x8 kf1 = ld8(&Ks[bufq][sw(kt * 16 + l16, 4 + quad)]);
            #pragma unroll
            for (int qb = 0; qb < 2; qb++) {
                f32x4 c = {};
                c = __builtin_amdgcn_mfma_f32_16x16x32_bf16(kf0, qf[qb][0], c, 0, 0, 0);
                c = __builtin_amdgcn_mfma_f32_16x16x32_bf16(kf1, qf[qb][1], c, 0, 0, 0);
                pk[qb][kt][0] = pkpair(__builtin_amdgcn_exp2f(c[0]),
                                       __builtin_amdgcn_exp2f(c[1]));
                pk[qb][kt][1] = pkpair(__builtin_amdgcn_exp2f(c[2]),
                                       __builtin_amdgcn_exp2f(c[3]));
            }
        }
    };

    // in-register quad transpose (permlane swaps) + rowsum
    // target: pf[qb][f] = A-frag, dword jp = keys (32f + 8*quad + 2jp, +1)
    auto do_permlane_osum = [&]() {
        #pragma unroll
        for (int qb = 0; qb < 2; qb++) {
            #pragma unroll
            for (int f = 0; f < 2; f++) {
                uint32_t a0 = pk[qb][2 * f][0], b0 = pk[qb][2 * f + 1][0];
                uint32_t a1 = pk[qb][2 * f][1], b1 = pk[qb][2 * f + 1][1];
                {
                    auto r = __builtin_amdgcn_permlane32_swap(a0, b0, false, false);
                    a0 = r[0]; b0 = r[1];
                }
                {
                    auto r = __builtin_amdgcn_permlane32_swap(a1, b1, false, false);
                    a1 = r[0]; b1 = r[1];
                }
                {
                    auto r = __builtin_amdgcn_permlane16_swap(a0, b0, false, false);
                    a0 = r[0]; b0 = r[1];
                }
                {
                    auto r = __builtin_amdgcn_permlane16_swap(a1, b1, false, false);
                    a1 = r[0]; b1 = r[1];
                }
                u32x4 d;
                d[0] = a0; d[1] = a1; d[2] = b0; d[3] = b1;
                pf[qb][f] = __builtin_bit_cast(bf16x8, d);
            }
            osum[qb] = __builtin_amdgcn_mfma_f32_16x16x32_bf16(pf[qb][0], ONES, osum[qb], 0, 0, 0);
            osum[qb] = __builtin_amdgcn_mfma_f32_16x16x32_bf16(pf[qb][1], ONES, osum[qb], 0, 0, 0);
        }
    };

    auto do_pv = [&](int tt) {
        const int bufv = tt & 1;
        #pragma unroll
        for (int db = 0; db < 4; db++) {
            bf16x8 vf0 = ld8(&Vt[bufv][sw(db * 16 + l16, quad)]);
            bf16x8 vf1 = ld8(&Vt[bufv][sw(db * 16 + l16, 4 + quad)]);
            #pragma unroll
            for (int qb = 0; qb < 2; qb++) {
                o[qb][db] = __builtin_amdgcn_mfma_f32_16x16x32_bf16(pf[qb][0], vf0, o[qb][db], 0, 0, 0);
                o[qb][db] = __builtin_amdgcn_mfma_f32_16x16x32_bf16(pf[qb][1], vf1, o[qb][db], 0, 0, 0);
            }
        }
    };

    constexpr int NT = SEQ / 64;

    // prologue: K0, V0, K1 staged; QKexp(0) computed
    stage_gll_sw(kbase,                      QKLD, Ks[0], wave, lane);
    stage_gll_sw(vbase,                      SEQ,  Vt[0], wave, lane);
    stage_gll_sw(kbase + (size_t)64 * QKLD,  QKLD, Ks[1], wave, lane);
    __syncthreads();
    do_qkexp(0);

    for (int t = 0; t < NT - 1; ++t) {
        __syncthreads();
        // stage K[t+2] into Ks[t&1] (QKexp(t) read of it finished pre-barrier);
        // stage V[t+1] into Vt[(t+1)&1] (PV(t-1) read finished pre-barrier)
        if (t + 2 < NT)
            stage_gll_sw(kbase + (size_t)(t + 2) * 64 * QKLD, QKLD, Ks[t & 1], wave, lane);
        stage_gll_sw(vbase + (t + 1) * 64, SEQ, Vt[(t + 1) & 1], wave, lane);

        do_permlane_osum();              // consumes pk(t) -> pf
        __builtin_amdgcn_s_setprio(1);
        do_pv(t);                        // MFMA: pf x Vt[t&1]
        do_qkexp(t + 1);                 // MFMA+exp2 -> pk(t+1), Ks[(t+1)&1]
        __builtin_amdgcn_s_setprio(0);
    }

    // tail: permlane + rowsum + PV of the last tile
    __syncthreads();
    do_permlane_osum();
    do_pv(NT - 1);

    // normalize + store (o, osum share C-layout: row=quad*4+r=q, col=l16=d)
    #pragma unroll
    for (int qb = 0; qb < 2; qb++)
        #pragma unroll
        for (int r = 0; r < 4; r++) {
            const float linv = __builtin_amdgcn_rcpf(osum[qb][r]);
            const int q = q0 + qb * 16 + quad * 4 + r;
            #pragma unroll
            for (int db = 0; db < 4; db++)
                outp[(brow + q) * DEMB + h * DH + db * 16 + l16] =
                    (__bf16)(o[qb][db][r] * linv);
        }
}

// ---------------------------------------------------------------------------
// GEMM2: out = attn @ w_out_bf16^T + b_out  (both via swizzled gll, fp32 out).
// MFMA operands SWAPPED so acc holds 4 consecutive n per fragment; epilogue
// stages fp32 through LDS (two 64-row passes over the 32KB As|Bs space) and
// does fully-coalesced float4 stores.
// ---------------------------------------------------------------------------
__global__ __launch_bounds__(256)
void gemm_out(const __bf16* __restrict__ A, const __bf16* __restrict__ W,
              const float* __restrict__ bias, float* __restrict__ C,
              int N, int K) {
    __shared__ __align__(16) __bf16 SMO[2 * 128 * 64];   // As|Bs, reused fp32
    __bf16* As = SMO;
    __bf16* Bs = SMO + 128 * 64;

    const int tid  = threadIdx.x;
    const int wave = tid >> 6, lane = tid & 63;
    const int quad = lane >> 4, l16 = lane & 15;
    const int m0 = blockIdx.x * 128, n0 = blockIdx.y * 128;
    const int wm = wave & 1, wn = wave >> 1;

    // acc[j][i]: output row-dim = n (quad*4+r), col-dim = m (l16)
    f32x4 acc[4][4] = {};

    for (int k0 = 0; k0 < K; k0 += 64) {
        __syncthreads();
        stage_gll(A + (size_t)m0 * K + k0, As, K, wave, lane);
        stage_gll(W + (size_t)n0 * K + k0, Bs, K, wave, lane);
        __syncthreads();
        #pragma unroll
        for (int ks = 0; ks < 2; ks++) {
            bf16x8 af[4], bf[4];
            #pragma unroll
            for (int t = 0; t < 4; t++) {
                af[t] = ld8(&As[sw(wm * 64 + t * 16 + l16, ks * 4 + quad)]);
                bf[t] = ld8(&Bs[sw(wn * 64 + t * 16 + l16, ks * 4 + quad)]);
            }
            #pragma unroll
            for (int j = 0; j < 4; j++)
                #pragma unroll
                for (int i = 0; i < 4; i++)
                    acc[j][i] = __builtin_amdgcn_mfma_f32_16x16x32_bf16(
                        bf[j], af[i], acc[j][i], 0, 0, 0);
        }
    }

    __syncthreads();   // all waves done reading As/Bs
    float* SMf = (float*)SMO;     // 64 rows x 128 cols fp32 per pass = 32KB

    #pragma unroll
    for (int p = 0; p < 2; p++) {
        if (p) __syncthreads();   // pass-0 reads done before pass-1 writes
        if (wm == p) {
            #pragma unroll
            for (int j = 0; j < 4; j++) {
                const int nl = wn * 64 + j * 16 + quad * 4;
                const float4 bv4 = *(const float4*)&bias[n0 + nl];
                const int chunkf = nl >> 2;              // 0..31 (16B chunks)
                #pragma unroll
                for (int i = 0; i < 4; i++) {
                    const int ml = i * 16 + l16;         // local row 0..63
                    const int physf = ((chunkf & 7) ^ (ml & 7)) | (chunkf & 24);
                    float4 v;
                    v.x = acc[j][i][0] + bv4.x;
                    v.y = acc[j][i][1] + bv4.y;
                    v.z = acc[j][i][2] + bv4.z;
                    v.w = acc[j][i][3] + bv4.w;
                    *(float4*)(&SMf[ml * 128 + physf * 4]) = v;
                }
            }
        }
        __syncthreads();
        // coalesced stores: 32 lanes cover one 512B row
        const int g2 = tid >> 5, li2 = tid & 31;
        #pragma unroll
        for (int it = 0; it < 8; it++) {
            const int row = it * 8 + g2;
            const int physf = ((li2 & 7) ^ (row & 7)) | (li2 & 24);
            float4 v = *(const float4*)&SMf[row * 128 + physf * 4];
            *(float4*)(&C[(size_t)(m0 + p * 64 + row) * N + n0 + li2 * 4]) = v;
        }
    }
}

// ---------------------------------------------------------------------------
extern "C" void kernel_launch(void* const* d_in, const int* in_sizes, int n_in,
                              void* d_out, int out_size, void* d_ws, size_t ws_size,
                              hipStream_t stream) {
    const float* x     = (const float*)d_in[0];
    const float* w_in  = (const float*)d_in[1];
    const float* b_in  = (const float*)d_in[2];
    const float* w_out = (const float*)d_in[3];
    const float* b_out = (const float*)d_in[4];

    __bf16* qk   = (__bf16*)d_ws;                    // 16384x1024 = 32 MB
    __bf16* vtb  = qk + (size_t)M_ROWS * QKLD;       // 4096x2048  = 16 MB
    __bf16* xbuf = vtb + (size_t)BATCH * DEMB * SEQ; // 16 MB, ALIASED with aout
    __bf16* aout = xbuf;                             // x_bf16 dead before attn writes
    __bf16* woutb = vtb;                             // vtb dead after attn
    __bf16* winb = (__bf16*)((char*)d_out + 24u * 1024 * 1024);  // 1.5 MB of d_out
    float*  outp = (float*)d_out;

    cvt_all<<<(NXQ + NWQ + 255) / 256, 256, 0, stream>>>(x, w_in, xbuf, winb);
    gemm_qkv<<<dim3(M_ROWS / 128, 12), 256, 0, stream>>>(xbuf, winb, b_in, qk, vtb);
    attn_flash<<<dim3(SEQ / 128, NH, BATCH), 256, 0, stream>>>(qk, vtb, aout);
    cvt_wout<<<NOQ / 256, 256, 0, stream>>>(w_out, woutb);
    gemm_out<<<dim3(M_ROWS / 128, DEMB / 128), 256, 0, stream>>>(
        aout, woutb, b_out, outp, DEMB, DEMB);
}

// Round 11
// 224.146 us; speedup vs baseline: 1.9058x; 1.0147x over previous
//
#include <hip/hip_runtime.h>
#include <stdint.h>

#define SEQ   2048
#define DEMB  512
#define NH    8
#define DH    64
#define BATCH 8
#define M_ROWS (BATCH * SEQ)   // 16384
#define QKLD  1024             // qk buffer row stride (Q|K)
#define QSCALE 0.18033688011112042f   // 0.125 * log2(e)

typedef __attribute__((ext_vector_type(8))) __bf16 bf16x8;
typedef __attribute__((ext_vector_type(4))) __bf16 bf16x4;
typedef __attribute__((ext_vector_type(4))) float  f32x4;
typedef __attribute__((ext_vector_type(8))) uint16_t u16x8;
typedef __attribute__((ext_vector_type(4))) uint32_t u32x4;

__device__ __forceinline__ void gll16(const __bf16* g, __bf16* l) {
    __builtin_amdgcn_global_load_lds(
        (__attribute__((address_space(1))) void*)(__bf16*)g,
        (__attribute__((address_space(3))) void*)l, 16, 0, 0);
}

__device__ __forceinline__ bf16x8 ld8(const __bf16* p) {
    return *(const bf16x8*)p;
}

// pack two fp32 -> bf16 pair via plain casts + integer merge.
// NOTE (round-8 lesson): do NOT use a bf16x2 vector-element-insert form here.
// That form fails SROA on this compiler, the loop-carried pk[][] aggregate
// becomes address-taken and spills to SCRATCH (WRITE_SIZE 16->549MB, attn
// 90->280us).  This scalar-cast + or form stays in registers.
__device__ __forceinline__ uint32_t pkpair(float a, float b) {
    const uint16_t lo = __builtin_bit_cast(uint16_t, (__bf16)a);
    const uint16_t hi = __builtin_bit_cast(uint16_t, (__bf16)b);
    return (uint32_t)lo | ((uint32_t)hi << 16);
}

// XOR-swizzled offset into a 64-wide bf16 LDS tile (8-elem chunks)
__device__ __forceinline__ int sw(int row, int chunk) {
    return row * 64 + ((chunk ^ (row & 7)) << 3);
}

// XOR-swizzled offset into a 32-wide bf16 LDS tile (8-elem chunks).
// Row = 64B = 16 banks: bank set depends on row&1 only, so spread the 4
// chunk slots with ((row>>1)&3) -> 2 lanes per 4-bank group = free (m136).
__device__ __forceinline__ int sw32(int row, int chunk) {
    return row * 32 + ((chunk ^ ((row >> 1) & 3)) << 3);
}

// stage 64x64 bf16 tile into swizzled LDS via gll16 (swizzle on global col)
__device__ __forceinline__ void stage_gll_sw(const __bf16* g, int gld,
                                             __bf16* l, int wave, int lane) {
    const int lr = lane >> 3;
    const int scol = ((lane & 7) ^ lr) * 8;
    #pragma unroll
    for (int i = 0; i < 2; i++) {
        const int r0 = i * 32 + wave * 8;
        gll16(g + (size_t)(r0 + lr) * gld + scol, l + r0 * 64);
    }
}

// stage 128x32 bf16 tile via gll16 (16B/lane), XOR-swizzled via pre-swizzled
// global source column (gll16 LDS dest must stay wave-linear).  Wave-call
// writes 16 rows of 64B; phys chunk (lane&3) holds logical chunk
// (lane&3)^((lr>>1)&3), lr = lane>>2; rows are 16-aligned per call so
// (row>>1)&3 == (lr>>1)&3, matching sw32() on the read side.
__device__ __forceinline__ void stage_gll32(const __bf16* src, __bf16* dst,
                                            int ld, int wave, int lane) {
    const int lr = lane >> 2;
    const int scol = ((lane & 3) ^ ((lr >> 1) & 3)) * 8;
    #pragma unroll
    for (int i = 0; i < 2; i++) {
        const int r0 = (i * 4 + wave) * 16;     // 0..112 step 16
        gll16(src + (size_t)(r0 + lr) * ld + scol, dst + r0 * 32);
    }
}

// ---------------------------------------------------------------------------
// fp32->bf16 converts
// ---------------------------------------------------------------------------
#define NXQ (M_ROWS * DEMB / 4)      // 2097152
#define NWQ (3 * DEMB * DEMB / 4)    // 196608
#define NOQ (DEMB * DEMB / 4)        // 65536

__global__ __launch_bounds__(256)
void cvt_all(const float* __restrict__ x, const float* __restrict__ w_in,
             __bf16* __restrict__ xb, __bf16* __restrict__ wb) {
    const int i = blockIdx.x * 256 + threadIdx.x;
    const float4* src;
    bf16x4* dst;
    if (i < NXQ) { src = (const float4*)x + i;         dst = (bf16x4*)xb + i; }
    else if (i < NXQ + NWQ) {
        const int j = i - NXQ;
        src = (const float4*)w_in + j;  dst = (bf16x4*)wb + j;
    } else return;
    const float4 v = *src;
    bf16x4 b;
    b[0] = (__bf16)v.x; b[1] = (__bf16)v.y;
    b[2] = (__bf16)v.z; b[3] = (__bf16)v.w;
    *dst = b;
}

__global__ __launch_bounds__(256)
void cvt_wout(const float* __restrict__ w, __bf16* __restrict__ wb) {
    const int i = blockIdx.x * 256 + threadIdx.x;
    if (i < NOQ) {
        const float4 v = ((const float4*)w)[i];
        bf16x4 b;
        b[0] = (__bf16)v.x; b[1] = (__bf16)v.y;
        b[2] = (__bf16)v.z; b[3] = (__bf16)v.w;
        ((bf16x4*)wb)[i] = b;
    }
}

// ---------------------------------------------------------------------------
// GEMM1: qkv = x_bf16 @ w_in_bf16^T + b_in.
// Round-11: K-loop DOUBLE-BUFFERED at BK=32 with constant 32KB LDS
// ([A0|A1|B0|B1] 8KB each) using attn's proven pattern: barrier ->
// issue stage(t+1) -> compute(t).  Staging latency overlaps compute
// (the old barrier;stage;barrier;compute form exposed it fully).
// Q cols pre-scaled by QSCALE.  Q,K -> qk[m][1024]; epilogues unchanged.
// ---------------------------------------------------------------------------
__global__ __launch_bounds__(256)
void gemm_qkv(const __bf16* __restrict__ A, const __bf16* __restrict__ W,
              const float* __restrict__ bias, __bf16* __restrict__ qk,
              __bf16* __restrict__ vt) {
    constexpr int K = DEMB;
    __shared__ __align__(16) __bf16 SM[128 * 128];   // [A0|A1|B0|B1]; reused for C

    const int tid  = threadIdx.x;
    const int wave = tid >> 6, lane = tid & 63;
    const int quad = lane >> 4, l16 = lane & 15;
    const int m0 = blockIdx.x * 128, n0 = blockIdx.y * 128;
    const int wm = wave & 1, wn = wave >> 1;
    const bool qkblk = (n0 < QKLD);

    // qkblk: acc[j][i], output row-dim = n (quad*4+r), col-dim = m (l16)
    // else : acc[i][j], output row-dim = m (quad*4+r), col-dim = n (l16)
    f32x4 acc[4][4] = {};

    const __bf16* Ab = A + (size_t)m0 * K;
    const __bf16* Wb = W + (size_t)n0 * K;

    stage_gll32(Ab, SM, K, wave, lane);
    stage_gll32(Wb, SM + 8192, K, wave, lane);

    for (int t = 0; t < K / 32; ++t) {
        __syncthreads();                 // drains stage(t); syncs buf reuse
        if (t + 1 < K / 32) {
            const int nb = (t + 1) & 1;
            stage_gll32(Ab + (t + 1) * 32, SM + nb * 4096, K, wave, lane);
            stage_gll32(Wb + (t + 1) * 32, SM + 8192 + nb * 4096, K, wave, lane);
        }
        const int buf = t & 1;
        bf16x8 af[4], bf[4];
        #pragma unroll
        for (int tt = 0; tt < 4; tt++) {
            af[tt] = ld8(&SM[buf * 4096 + sw32(wm * 64 + tt * 16 + l16, quad)]);
            bf[tt] = ld8(&SM[8192 + buf * 4096 + sw32(wn * 64 + tt * 16 + l16, quad)]);
        }
        if (qkblk) {
            #pragma unroll
            for (int j = 0; j < 4; j++)
                #pragma unroll
                for (int i = 0; i < 4; i++)
                    acc[j][i] = __builtin_amdgcn_mfma_f32_16x16x32_bf16(
                        bf[j], af[i], acc[j][i], 0, 0, 0);
        } else {
            #pragma unroll
            for (int i = 0; i < 4; i++)
                #pragma unroll
                for (int j = 0; j < 4; j++)
                    acc[i][j] = __builtin_amdgcn_mfma_f32_16x16x32_bf16(
                        af[i], bf[j], acc[i][j], 0, 0, 0);
        }
    }

    __syncthreads();   // all waves done reading tiles before SM reuse

    if (qkblk) {
        const float scl = (n0 < DEMB) ? QSCALE : 1.0f;   // pre-scale Q only
        // stage C[m][n] into swizzled SM: bf16x4 = 4 consecutive n per write
        #pragma unroll
        for (int j = 0; j < 4; j++) {
            const int nl = wn * 64 + j * 16 + quad * 4;
            const float4 bv4 = *(const float4*)&bias[n0 + nl];
            const int chunk = nl >> 3;                   // wn*8 + j*2 + (quad>>1)
            #pragma unroll
            for (int i = 0; i < 4; i++) {
                const int ml = wm * 64 + i * 16 + l16;
                bf16x4 pk;
                pk[0] = (__bf16)((acc[j][i][0] + bv4.x) * scl);
                pk[1] = (__bf16)((acc[j][i][1] + bv4.y) * scl);
                pk[2] = (__bf16)((acc[j][i][2] + bv4.z) * scl);
                pk[3] = (__bf16)((acc[j][i][3] + bv4.w) * scl);
                const int phys = ((chunk & 7) ^ (ml & 7)) | (chunk & 8);
                *(bf16x4*)(&SM[ml * 128 + phys * 8 + (nl & 7)]) = pk;
            }
        }
        __syncthreads();
        // coalesced stores: 16 lanes cover one 256B row of qk
        const int g = tid >> 4, li = tid & 15;
        #pragma unroll
        for (int it = 0; it < 8; it++) {
            const int row = it * 16 + g;
            const int phys = ((li & 7) ^ (row & 7)) | (li & 8);
            bf16x8 v = ld8(&SM[row * 128 + phys * 8]);
            *(bf16x8*)(qk + (size_t)(m0 + row) * QKLD + n0 + li * 8) = v;
        }
    } else {
        // V block: transpose 128(hd) x 128(s) through swizzled LDS
        const int hd0 = n0 - QKLD;             // 0,128,256,384
        const int bb = m0 >> 11, s0 = m0 & (SEQ - 1);
        #pragma unroll
        for (int j = 0; j < 4; j++) {
            const int n = n0 + wn * 64 + j * 16 + l16;
            const float bv = bias[n];
            const int hdl = wn * 64 + j * 16 + l16;      // local hd row
            #pragma unroll
            for (int i = 0; i < 4; i++) {
                const int sl = wm * 64 + i * 16 + quad * 4;  // local s (4-aligned)
                bf16x4 pk;
                #pragma unroll
                for (int r = 0; r < 4; r++)
                    pk[r] = (__bf16)(acc[i][j][r] + bv);
                const int chunk = sl >> 3;               // 0..15
                const int phys = (((chunk & 7) ^ (hdl & 7)) | (chunk & 8));
                *(bf16x4*)(&SM[hdl * 128 + phys * 8 + (sl & 7)]) = pk;
            }
        }
        __syncthreads();
        // coalesced stores: 16 lanes cover one 256B row
        const int g = tid >> 4, li = tid & 15;
        #pragma unroll
        for (int it = 0; it < 8; it++) {
            const int row = it * 16 + g;
            const int phys = (((li & 7) ^ (row & 7)) | (li & 8));
            bf16x8 v = ld8(&SM[row * 128 + phys * 8]);
            *(bf16x8*)(vt + ((size_t)(bb * DEMB + hd0 + row)) * SEQ + s0 + li * 8) = v;
        }
    }
}

// ---------------------------------------------------------------------------
// Flash attention, S^T formulation, software-pipelined across k-tiles.
// Loop-carried state is the PACKED bf16 score tile pk[2][4][2] (16 regs):
// exp2+pack fused into the QK cluster.  Body overlaps {permlane+osum+PV}(t)
// with {QK+exp2+pack}(t+1) in the same wave.
// Direct blockIdx mapping (XCD head-pinning remap measured as L2 thrash).
// __launch_bounds__(256,4): 60 VGPR, 4 blocks/CU, occupancy ~36%.
// Buffering: K staged 2-ahead into Ks[t&1], V 1-ahead; one barrier per iter.
// LDS = 32KB.  (Round-9 proven configuration: attn 88.7us.)  UNCHANGED.
// ---------------------------------------------------------------------------
__global__ __launch_bounds__(256, 4)
void attn_flash(const __bf16* __restrict__ qk, const __bf16* __restrict__ vt,
                __bf16* __restrict__ outp) {
    const int qt = blockIdx.x, h = blockIdx.y, b = blockIdx.z;
    const int tid  = threadIdx.x;
    const int wave = tid >> 6, lane = tid & 63;
    const int quad = lane >> 4, l16 = lane & 15;

    __shared__ __align__(16) __bf16 Ks[2][64 * 64];   // 16 KB
    __shared__ __align__(16) __bf16 Vt[2][64 * 64];   // 16 KB

    const size_t brow = (size_t)b * SEQ;
    const int q0 = qt * 128 + wave * 32;
    const __bf16* kbase = qk + brow * QKLD + DEMB + h * DH;
    const __bf16* vbase = vt + ((size_t)(b * DEMB + h * DH)) * SEQ;

    const u16x8 one16 = {0x3F80, 0x3F80, 0x3F80, 0x3F80,
                         0x3F80, 0x3F80, 0x3F80, 0x3F80};
    const bf16x8 ONES = __builtin_bit_cast(bf16x8, one16);

    // Q fragments (B-operand: B[k=quad*8+j][n=l16] = Q[q=l16][d])
    bf16x8 qf[2][2];
    #pragma unroll
    for (int qb = 0; qb < 2; qb++) {
        const __bf16* qp = qk + (brow + q0 + qb * 16 + l16) * QKLD + h * DH + quad * 8;
        qf[qb][0] = ld8(qp);
        qf[qb][1] = ld8(qp + 32);
    }

    f32x4 o[2][4] = {};
    f32x4 osum[2] = {};
    uint32_t pk[2][4][2];    // packed exp2'd scores, carried across iterations
    bf16x8 pf[2][2];         // P fragments of the tile being PV'd

    // QK^T + fused exp2 + pack for tile tt:
    // pk[qb][kt][rp] = bf16 pair of keys (16kt + 4*quad + 2rp, +1) at q=l16
    auto do_qkexp = [&](int tt) {
        const int bufq = tt & 1;
        #pragma unroll
        for (int kt = 0; kt < 4; kt++) {
            bf16x8 kf0 = ld8(&Ks[bufq][sw(kt * 16 + l16, quad)]);
            bf16x8 kf1 = ld8(&Ks[bufq][sw(kt * 16 + l16, 4 + quad)]);
            #pragma unroll
            for (int qb = 0; qb < 2; qb++) {
                f32x4 c = {};
                c = __builtin_amdgcn_mfma_f32_16x16x32_bf16(kf0, qf[qb][0], c, 0, 0, 0);
                c = __builtin_amdgcn_mfma_f32_16x16x32_bf16(kf1, qf[qb][1], c, 0, 0, 0);
                pk[qb][kt][0] = pkpair(__builtin_amdgcn_exp2f(c[0]),
                                       __builtin_amdgcn_exp2f(c[1]));
                pk[qb][kt][1] = pkpair(__builtin_amdgcn_exp2f(c[2]),
                                       __builtin_amdgcn_exp2f(c[3]));
            }
        }
    };

    // in-register quad transpose (permlane swaps) + rowsum
    // target: pf[qb][f] = A-frag, dword jp = keys (32f + 8*quad + 2jp, +1)
    auto do_permlane_osum = [&]() {
        #pragma unroll
        for (int qb = 0; qb < 2; qb++) {
            #pragma unroll
            for (int f = 0; f < 2; f++) {
                uint32_t a0 = pk[qb][2 * f][0], b0 = pk[qb][2 * f + 1][0];
                uint32_t a1 = pk[qb][2 * f][1], b1 = pk[qb][2 * f + 1][1];
                {
                    auto r = __builtin_amdgcn_permlane32_swap(a0, b0, false, false);
                    a0 = r[0]; b0 = r[1];
                }
                {
                    auto r = __builtin_amdgcn_permlane32_swap(a1, b1, false, false);
                    a1 = r[0]; b1 = r[1];
                }
                {
                    auto r = __builtin_amdgcn_permlane16_swap(a0, b0, false, false);
                    a0 = r[0]; b0 = r[1];
                }
                {
                    auto r = __builtin_amdgcn_permlane16_swap(a1, b1, false, false);
                    a1 = r[0]; b1 = r[1];
                }
                u32x4 d;
                d[0] = a0; d[1] = a1; d[2] = b0; d[3] = b1;
                pf[qb][f] = __builtin_bit_cast(bf16x8, d);
            }
            osum[qb] = __builtin_amdgcn_mfma_f32_16x16x32_bf16(pf[qb][0], ONES, osum[qb], 0, 0, 0);
            osum[qb] = __builtin_amdgcn_mfma_f32_16x16x32_bf16(pf[qb][1], ONES, osum[qb], 0, 0, 0);
        }
    };

    auto do_pv = [&](int tt) {
        const int bufv = tt & 1;
        #pragma unroll
        for (int db = 0; db < 4; db++) {
            bf16x8 vf0 = ld8(&Vt[bufv][sw(db * 16 + l16, quad)]);
            bf16x8 vf1 = ld8(&Vt[bufv][sw(db * 16 + l16, 4 + quad)]);
            #pragma unroll
            for (int qb = 0; qb < 2; qb++) {
                o[qb][db] = __builtin_amdgcn_mfma_f32_16x16x32_bf16(pf[qb][0], vf0, o[qb][db], 0, 0, 0);
                o[qb][db] = __builtin_amdgcn_mfma_f32_16x16x32_bf16(pf[qb][1], vf1, o[qb][db], 0, 0, 0);
            }
        }
    };

    constexpr int NT = SEQ / 64;

    // prologue: K0, V0, K1 staged; QKexp(0) computed
    stage_gll_sw(kbase,                      QKLD, Ks[0], wave, lane);
    stage_gll_sw(vbase,                      SEQ,  Vt[0], wave, lane);
    stage_gll_sw(kbase + (size_t)64 * QKLD,  QKLD, Ks[1], wave, lane);
    __syncthreads();
    do_qkexp(0);

    for (int t = 0; t < NT - 1; ++t) {
        __syncthreads();
        // stage K[t+2] into Ks[t&1] (QKexp(t) read of it finished pre-barrier);
        // stage V[t+1] into Vt[(t+1)&1] (PV(t-1) read finished pre-barrier)
        if (t + 2 < NT)
            stage_gll_sw(kbase + (size_t)(t + 2) * 64 * QKLD, QKLD, Ks[t & 1], wave, lane);
        stage_gll_sw(vbase + (t + 1) * 64, SEQ, Vt[(t + 1) & 1], wave, lane);

        do_permlane_osum();              // consumes pk(t) -> pf
        __builtin_amdgcn_s_setprio(1);
        do_pv(t);                        // MFMA: pf x Vt[t&1]
        do_qkexp(t + 1);                 // MFMA+exp2 -> pk(t+1), Ks[(t+1)&1]
        __builtin_amdgcn_s_setprio(0);
    }

    // tail: permlane + rowsum + PV of the last tile
    __syncthreads();
    do_permlane_osum();
    do_pv(NT - 1);

    // normalize + store (o, osum share C-layout: row=quad*4+r=q, col=l16=d)
    #pragma unroll
    for (int qb = 0; qb < 2; qb++)
        #pragma unroll
        for (int r = 0; r < 4; r++) {
            const float linv = __builtin_amdgcn_rcpf(osum[qb][r]);
            const int q = q0 + qb * 16 + quad * 4 + r;
            #pragma unroll
            for (int db = 0; db < 4; db++)
                outp[(brow + q) * DEMB + h * DH + db * 16 + l16] =
                    (__bf16)(o[qb][db][r] * linv);
        }
}

// ---------------------------------------------------------------------------
// GEMM2: out = attn @ w_out_bf16^T + b_out  (fp32 out).
// Same BK=32 double-buffered staging as gemm_qkv; 32KB LDS [A0|A1|B0|B1].
// MFMA operands SWAPPED so acc holds 4 consecutive n per fragment; epilogue
// stages fp32 through LDS (two 64-row passes) + coalesced float4 stores.
// ---------------------------------------------------------------------------
__global__ __launch_bounds__(256)
void gemm_out(const __bf16* __restrict__ A, const __bf16* __restrict__ W,
              const float* __restrict__ bias, float* __restrict__ C,
              int N, int K) {
    __shared__ __align__(16) __bf16 SMO[128 * 128];   // [A0|A1|B0|B1]; reused fp32

    const int tid  = threadIdx.x;
    const int wave = tid >> 6, lane = tid & 63;
    const int quad = lane >> 4, l16 = lane & 15;
    const int m0 = blockIdx.x * 128, n0 = blockIdx.y * 128;
    const int wm = wave & 1, wn = wave >> 1;

    // acc[j][i]: output row-dim = n (quad*4+r), col-dim = m (l16)
    f32x4 acc[4][4] = {};

    const __bf16* Ab = A + (size_t)m0 * K;
    const __bf16* Wb = W + (size_t)n0 * K;

    stage_gll32(Ab, SMO, K, wave, lane);
    stage_gll32(Wb, SMO + 8192, K, wave, lane);

    for (int t = 0; t < K / 32; ++t) {
        __syncthreads();
        if (t + 1 < K / 32) {
            const int nb = (t + 1) & 1;
            stage_gll32(Ab + (t + 1) * 32, SMO + nb * 4096, K, wave, lane);
            stage_gll32(Wb + (t + 1) * 32, SMO + 8192 + nb * 4096, K, wave, lane);
        }
        const int buf = t & 1;
        bf16x8 af[4], bf[4];
        #pragma unroll
        for (int tt = 0; tt < 4; tt++) {
            af[tt] = ld8(&SMO[buf * 4096 + sw32(wm * 64 + tt * 16 + l16, quad)]);
            bf[tt] = ld8(&SMO[8192 + buf * 4096 + sw32(wn * 64 + tt * 16 + l16, quad)]);
        }
        #pragma unroll
        for (int j = 0; j < 4; j++)
            #pragma unroll
            for (int i = 0; i < 4; i++)
                acc[j][i] = __builtin_amdgcn_mfma_f32_16x16x32_bf16(
                    bf[j], af[i], acc[j][i], 0, 0, 0);
    }

    __syncthreads();   // all waves done reading tiles
    float* SMf = (float*)SMO;     // 64 rows x 128 cols fp32 per pass = 32KB

    #pragma unroll
    for (int p = 0; p < 2; p++) {
        if (p) __syncthreads();   // pass-0 reads done before pass-1 writes
        if (wm == p) {
            #pragma unroll
            for (int j = 0; j < 4; j++) {
                const int nl = wn * 64 + j * 16 + quad * 4;
                const float4 bv4 = *(const float4*)&bias[n0 + nl];
                const int chunkf = nl >> 2;              // 0..31 (16B chunks)
                #pragma unroll
                for (int i = 0; i < 4; i++) {
                    const int ml = i * 16 + l16;         // local row 0..63
                    const int physf = ((chunkf & 7) ^ (ml & 7)) | (chunkf & 24);
                    float4 v;
                    v.x = acc[j][i][0] + bv4.x;
                    v.y = acc[j][i][1] + bv4.y;
                    v.z = acc[j][i][2] + bv4.z;
                    v.w = acc[j][i][3] + bv4.w;
                    *(float4*)(&SMf[ml * 128 + physf * 4]) = v;
                }
            }
        }
        __syncthreads();
        // coalesced stores: 32 lanes cover one 512B row
        const int g2 = tid >> 5, li2 = tid & 31;
        #pragma unroll
        for (int it = 0; it < 8; it++) {
            const int row = it * 8 + g2;
            const int physf = ((li2 & 7) ^ (row & 7)) | (li2 & 24);
            float4 v = *(const float4*)&SMf[row * 128 + physf * 4];
            *(float4*)(&C[(size_t)(m0 + p * 64 + row) * N + n0 + li2 * 4]) = v;
        }
    }
}

// ---------------------------------------------------------------------------
extern "C" void kernel_launch(void* const* d_in, const int* in_sizes, int n_in,
                              void* d_out, int out_size, void* d_ws, size_t ws_size,
                              hipStream_t stream) {
    const float* x     = (const float*)d_in[0];
    const float* w_in  = (const float*)d_in[1];
    const float* b_in  = (const float*)d_in[2];
    const float* w_out = (const float*)d_in[3];
    const float* b_out = (const float*)d_in[4];

    __bf16* qk   = (__bf16*)d_ws;                    // 16384x1024 = 32 MB
    __bf16* vtb  = qk + (size_t)M_ROWS * QKLD;       // 4096x2048  = 16 MB
    __bf16* xbuf = vtb + (size_t)BATCH * DEMB * SEQ; // 16 MB, ALIASED with aout
    __bf16* aout = xbuf;                             // x_bf16 dead before attn writes
    __bf16* woutb = vtb;                             // vtb dead after attn
    __bf16* winb = (__bf16*)((char*)d_out + 24u * 1024 * 1024);  // 1.5 MB of d_out
    float*  outp = (float*)d_out;

    cvt_all<<<(NXQ + NWQ + 255) / 256, 256, 0, stream>>>(x, w_in, xbuf, winb);
    gemm_qkv<<<dim3(M_ROWS / 128, 12), 256, 0, stream>>>(xbuf, winb, b_in, qk, vtb);
    attn_flash<<<dim3(SEQ / 128, NH, BATCH), 256, 0, stream>>>(qk, vtb, aout);
    cvt_wout<<<NOQ / 256, 256, 0, stream>>>(w_out, woutb);
    gemm_out<<<dim3(M_ROWS / 128, DEMB / 128), 256, 0, stream>>>(
        aout, woutb, b_out, outp, DEMB, DEMB);
}